// Round 5
// baseline (982.492 us; speedup 1.0000x reference)
//
#include <hip/hip_runtime.h>
#include <hip/hip_bf16.h>
#include <math.h>

namespace {
constexpr int SEQ  = 1024;
constexpr int NE   = 128;

__device__ __forceinline__ float rcp_fast(float x) {
  return __builtin_amdgcn_rcpf(x);
}

__device__ __forceinline__ float gelu_fast(float x) {
  float x2 = x * x;
  float t = fmaf(x2, -0.1029443f, -2.3022093f);
  return x * rcp_fast(1.0f + exp2f(x * t));
}

__device__ __forceinline__ float tanh_fast(float x) {
  return 1.0f - 2.0f * rcp_fast(1.0f + exp2f(x * 2.8853901f));
}

__device__ __forceinline__ float sigmoid_fast(float x) {
  return rcp_fast(1.0f + exp2f(x * -1.4426950f));
}

__device__ __forceinline__ void atomAddF(float* p, float v) {
  unsafeAtomicAdd(p, v);   // hw global_atomic_add_f32
}

// ---------------------------------------------------------------- zero
__global__ __launch_bounds__(256) void zero_kernel(float4* __restrict__ p) {
  p[(size_t)blockIdx.x * 256 + threadIdx.x] = make_float4(0.f, 0.f, 0.f, 0.f);
}

// ---------------------------------------------------------------- pos add
__global__ __launch_bounds__(256) void posadd_kernel(
    const float* __restrict__ emb, const float* __restrict__ pos,
    float* __restrict__ x) {
  int i = blockIdx.x * 256 + threadIdx.x;      // float4 index; total 786432
  const int perB = SEQ * 768 / 4;              // 196608
  int pi = i - (i / perB) * perB;
  float4 e4 = ((const float4*)emb)[i];
  float4 p4 = ((const float4*)pos)[pi];
  e4.x += p4.x; e4.y += p4.y; e4.z += p4.z; e4.w += p4.w;
  ((float4*)x)[i] = e4;
}

// ---------------------------------------------------------------- context mean
__global__ __launch_bounds__(256) void ctxmean_kernel(
    const float* __restrict__ x, float* __restrict__ ctxv) {
  int b = blockIdx.x / 12, chunk = blockIdx.x % 12;
  int lane = threadIdx.x & 63, sg = threadIdx.x >> 6;
  int d = chunk * 64 + lane;
  float acc = 0.f;
  const float* xb = x + ((size_t)b * SEQ + sg) * 768 + d;
  for (int s = sg; s < SEQ; s += 4) { acc += *xb; xb += 4 * 768; }
  __shared__ float red[4][64];
  red[sg][lane] = acc;
  __syncthreads();
  if (threadIdx.x < 64) {
    float t = red[0][threadIdx.x] + red[1][threadIdx.x] +
              red[2][threadIdx.x] + red[3][threadIdx.x];
    ctxv[b * 768 + chunk * 64 + threadIdx.x] = t * (1.0f / 1024.0f);
  }
}

// ---------------------------------------------------------------- legacy small GEMM (kept for C1, M=4)
__global__ __launch_bounds__(256) void gemm768_kernel(
    const float* __restrict__ A, const float* __restrict__ W,
    const float* __restrict__ bias, float* __restrict__ C, int M) {
  __shared__ __align__(16) float sA[16][68];
  __shared__ __align__(16) float sB[16][68];
  const int bm = blockIdx.x * 64;
  const int bn = blockIdx.y * 64;
  const int tid = threadIdx.x;
  const int tm = (tid >> 4) * 4;
  const int tn = (tid & 15) * 4;
  const int lm = tid >> 2, lkq = (tid & 3) * 4;
  const int lkk = tid >> 4, lnq = (tid & 15) * 4;
  float acc[4][4] = {};
  for (int k0 = 0; k0 < 768; k0 += 16) {
    float4 av = make_float4(0.f, 0.f, 0.f, 0.f);
    if (bm + lm < M) av = *(const float4*)&A[(size_t)(bm + lm) * 768 + k0 + lkq];
    float4 wv = *(const float4*)&W[(size_t)(k0 + lkk) * 768 + bn + lnq];
    __syncthreads();
    sA[lkq + 0][lm] = av.x; sA[lkq + 1][lm] = av.y;
    sA[lkq + 2][lm] = av.z; sA[lkq + 3][lm] = av.w;
    *(float4*)&sB[lkk][lnq] = wv;
    __syncthreads();
#pragma unroll
    for (int kk = 0; kk < 16; ++kk) {
      float4 a = *(const float4*)&sA[kk][tm];
      float4 w = *(const float4*)&sB[kk][tn];
      acc[0][0] += a.x * w.x; acc[0][1] += a.x * w.y; acc[0][2] += a.x * w.z; acc[0][3] += a.x * w.w;
      acc[1][0] += a.y * w.x; acc[1][1] += a.y * w.y; acc[1][2] += a.y * w.z; acc[1][3] += a.y * w.w;
      acc[2][0] += a.z * w.x; acc[2][1] += a.z * w.y; acc[2][2] += a.z * w.z; acc[2][3] += a.z * w.w;
      acc[3][0] += a.w * w.x; acc[3][1] += a.w * w.y; acc[3][2] += a.w * w.z; acc[3][3] += a.w * w.w;
    }
  }
#pragma unroll
  for (int i = 0; i < 4; ++i) {
    int row = bm + tm + i;
    if (row < M) {
#pragma unroll
      for (int j = 0; j < 4; ++j) {
        float o = acc[i][j];
        if (bias) o += bias[bn + tn + j];
        C[(size_t)row * 768 + bn + tn + j] = o;
      }
    }
  }
}

// ---------------------------------------------------------------- split-K GEMM, 128x128 tile, 8x8 micro, 256 threads
// C[sel] += A-tile @ W[sel]-strip over K-slice kb; grid (M/128, 6, nmat*ks)
struct GemmSet {
  const float* W[4];
  const float* bias[4];
  float* C[4];
};

__global__ __launch_bounds__(256) void gemm_splitk_kernel(
    const float* __restrict__ A, GemmSet gs, int ks, int KB) {
  __shared__ __align__(16) float sA[16][132];
  __shared__ __align__(16) float sB[16][132];
  const int sel = blockIdx.z / ks;
  const int kb  = blockIdx.z % ks;
  const float* __restrict__ W = gs.W[sel];
  const float* __restrict__ bias = gs.bias[sel];
  float* __restrict__ C = gs.C[sel];
  const int bm = blockIdx.x * 128;
  const int bn = blockIdx.y * 128;
  const int t = threadIdx.x;
  const int ar = t >> 1, akq = (t & 1) * 8;       // A loader: 2 float4
  const int bkr = t >> 4, bc = (t & 15) * 8;      // W loader: 2 float4
  const int ty = t >> 4, tx = t & 15;             // 8 rows x (4+4) cols
  const int kbeg = kb * KB, kend = kbeg + KB;

  const float* __restrict__ Ap = A + (size_t)(bm + ar) * 768 + akq;
  const float* __restrict__ Wp = W + (size_t)bkr * 768 + bn + bc;

  float4 a0 = *(const float4*)(Ap + kbeg);
  float4 a1 = *(const float4*)(Ap + kbeg + 4);
  const float* wr0 = Wp + (size_t)kbeg * 768;
  float4 w0 = *(const float4*)(wr0);
  float4 w1 = *(const float4*)(wr0 + 4);

  float acc[8][8] = {};
  for (int k0 = kbeg; k0 < kend; k0 += 16) {
    __syncthreads();
    sA[akq + 0][ar] = a0.x; sA[akq + 1][ar] = a0.y;
    sA[akq + 2][ar] = a0.z; sA[akq + 3][ar] = a0.w;
    sA[akq + 4][ar] = a1.x; sA[akq + 5][ar] = a1.y;
    sA[akq + 6][ar] = a1.z; sA[akq + 7][ar] = a1.w;
    *(float4*)&sB[bkr][bc]     = w0;
    *(float4*)&sB[bkr][bc + 4] = w1;
    __syncthreads();
    if (k0 + 16 < kend) {     // prefetch next slice
      a0 = *(const float4*)(Ap + k0 + 16);
      a1 = *(const float4*)(Ap + k0 + 20);
      const float* wr = Wp + (size_t)(k0 + 16) * 768;
      w0 = *(const float4*)(wr);
      w1 = *(const float4*)(wr + 4);
    }
#pragma unroll
    for (int kk = 0; kk < 16; ++kk) {
      float4 x0 = *(const float4*)&sA[kk][ty * 8];
      float4 x1 = *(const float4*)&sA[kk][ty * 8 + 4];
      float4 y0 = *(const float4*)&sB[kk][tx * 4];
      float4 y1 = *(const float4*)&sB[kk][64 + tx * 4];
      float xa[8] = {x0.x, x0.y, x0.z, x0.w, x1.x, x1.y, x1.z, x1.w};
      float yb[8] = {y0.x, y0.y, y0.z, y0.w, y1.x, y1.y, y1.z, y1.w};
#pragma unroll
      for (int i = 0; i < 8; ++i)
#pragma unroll
        for (int j = 0; j < 8; ++j)
          acc[i][j] += xa[i] * yb[j];
    }
  }

  float b0a[4], b1a[4];
  const bool addb = (kb == 0) && (bias != nullptr);
#pragma unroll
  for (int j = 0; j < 4; ++j) {
    b0a[j] = addb ? bias[bn + tx * 4 + j] : 0.0f;
    b1a[j] = addb ? bias[bn + 64 + tx * 4 + j] : 0.0f;
  }
#pragma unroll
  for (int i = 0; i < 8; ++i) {
    float* crow = C + (size_t)(bm + ty * 8 + i) * 768;
#pragma unroll
    for (int j = 0; j < 4; ++j) {
      atomAddF(crow + bn + tx * 4 + j,      acc[i][j]     + b0a[j]);
      atomAddF(crow + bn + 64 + tx * 4 + j, acc[i][4 + j] + b1a[j]);
    }
  }
}

// ---------------------------------------------------------------- fused K+V GEMM, 128x128 tile, 8x8 micro, 256 threads,
// split-K x2, atomic transposed (B,H,S,64) output
__global__ __launch_bounds__(256) void kv_gemm_kernel(
    const float* __restrict__ A,
    const float* __restrict__ Wk, const float* __restrict__ bk,
    const float* __restrict__ Wv, const float* __restrict__ bv,
    float* __restrict__ k2, float* __restrict__ v2) {
  __shared__ __align__(16) float sA[16][132];
  __shared__ __align__(16) float sB[16][132];
  const int bm = blockIdx.x * 128;
  const bool isV = blockIdx.y >= 6;
  const int bn = (blockIdx.y % 6) * 128;     // 2 heads
  const int kb = blockIdx.z;                 // 0/1
  const float* __restrict__ W = isV ? Wv : Wk;
  const float* __restrict__ bias = isV ? bv : bk;
  float* __restrict__ out = isV ? v2 : k2;
  const int t = threadIdx.x;
  const int ar = t >> 1, akq = (t & 1) * 8;
  const int bkr = t >> 4, bc = (t & 15) * 8;
  const int ty = t >> 4, tx = t & 15;
  const int kbeg = kb * 384, kend = kbeg + 384;

  const float* __restrict__ Ap = A + (size_t)(bm + ar) * 768 + akq;
  const float* __restrict__ Wp = W + (size_t)bkr * 768 + bn + bc;

  float4 a0 = *(const float4*)(Ap + kbeg);
  float4 a1 = *(const float4*)(Ap + kbeg + 4);
  const float* wr0 = Wp + (size_t)kbeg * 768;
  float4 w0 = *(const float4*)(wr0);
  float4 w1 = *(const float4*)(wr0 + 4);

  float acc[8][8] = {};
  for (int k0 = kbeg; k0 < kend; k0 += 16) {
    __syncthreads();
    sA[akq + 0][ar] = a0.x; sA[akq + 1][ar] = a0.y;
    sA[akq + 2][ar] = a0.z; sA[akq + 3][ar] = a0.w;
    sA[akq + 4][ar] = a1.x; sA[akq + 5][ar] = a1.y;
    sA[akq + 6][ar] = a1.z; sA[akq + 7][ar] = a1.w;
    *(float4*)&sB[bkr][bc]     = w0;
    *(float4*)&sB[bkr][bc + 4] = w1;
    __syncthreads();
    if (k0 + 16 < kend) {
      a0 = *(const float4*)(Ap + k0 + 16);
      a1 = *(const float4*)(Ap + k0 + 20);
      const float* wr = Wp + (size_t)(k0 + 16) * 768;
      w0 = *(const float4*)(wr);
      w1 = *(const float4*)(wr + 4);
    }
#pragma unroll
    for (int kk = 0; kk < 16; ++kk) {
      float4 x0 = *(const float4*)&sA[kk][ty * 8];
      float4 x1 = *(const float4*)&sA[kk][ty * 8 + 4];
      float4 y0 = *(const float4*)&sB[kk][tx * 4];
      float4 y1 = *(const float4*)&sB[kk][64 + tx * 4];
      float xa[8] = {x0.x, x0.y, x0.z, x0.w, x1.x, x1.y, x1.z, x1.w};
      float yb[8] = {y0.x, y0.y, y0.z, y0.w, y1.x, y1.y, y1.z, y1.w};
#pragma unroll
      for (int i = 0; i < 8; ++i)
#pragma unroll
        for (int j = 0; j < 8; ++j)
          acc[i][j] += xa[i] * yb[j];
    }
  }

  const int bidx = bm >> 10;
  const int s_base = bm & 1023;
  const int h0 = bn >> 6;
  float bs0[4], bs1[4];
#pragma unroll
  for (int j = 0; j < 4; ++j) {
    bs0[j] = (kb == 0) ? bias[bn + tx * 4 + j] : 0.0f;
    bs1[j] = (kb == 0) ? bias[bn + 64 + tx * 4 + j] : 0.0f;
  }
  float* o0 = out + ((size_t)(bidx * 12 + h0)) * 65536 + tx * 4;
  float* o1 = out + ((size_t)(bidx * 12 + h0 + 1)) * 65536 + tx * 4;
#pragma unroll
  for (int i = 0; i < 8; ++i) {
    int s = s_base + ty * 8 + i;
#pragma unroll
    for (int j = 0; j < 4; ++j) {
      atomAddF(o0 + (size_t)s * 64 + j, acc[i][j]     + bs0[j]);
      atomAddF(o1 + (size_t)s * 64 + j, acc[i][4 + j] + bs1[j]);
    }
  }
}

// ---------------------------------------------------------------- flash-style attention, 16 queries/block, (B,H,S,64) K/V
__global__ __launch_bounds__(256) void attn2_kernel(
    const float* __restrict__ q, const float* __restrict__ k2,
    const float* __restrict__ v2, float* __restrict__ ctx,
    float* __restrict__ invsum) {
  __shared__ float p[16][1028];
  __shared__ float4 sK[128 * 16];         // swizzled: [s][dq ^ (s&7)]
  __shared__ float4 sQ[16][16];
  __shared__ float linv[16];
  __shared__ float4 part[4][4][4][16];    // [sq][nq][i][dq]

  // XCD-aware remap: one (b,h)'s 8 q-group blocks land on one XCD
  const int xcd = blockIdx.x & 7;
  const int slot = blockIdx.x >> 3;       // 0..47
  const int bh = xcd * 6 + (slot >> 3);   // 0..47
  const int ng = slot & 7;
  const int b = bh / 12, h = bh % 12;
  const int t = threadIdx.x;

  {  // stage Q, fold 1/sqrt(64)
    int nn = t >> 4, dq = t & 15;
    float4 qv = *(const float4*)&q[(size_t)(ng * 16 + nn) * 768 + h * 64 + dq * 4];
    qv.x *= 0.125f; qv.y *= 0.125f; qv.z *= 0.125f; qv.w *= 0.125f;
    sQ[nn][dq] = qv;
  }
  const float4* kbh = (const float4*)(k2 + ((size_t)(b * 12 + h)) * 1024 * 64);
  const float4* vbh = (const float4*)(v2 + ((size_t)(b * 12 + h)) * 1024 * 64);

  const int npair = t >> 5;               // 0..7
  const int g = t & 31;
  const int n0 = npair * 2, n1 = n0 + 1;

  // ---- QK^T into p ----
  for (int c = 0; c < 8; ++c) {
    __syncthreads();
#pragma unroll
    for (int w = 0; w < 8; ++w) {
      int fi = w * 256 + t;
      int sl = fi >> 4, dq = fi & 15;
      sK[sl * 16 + (dq ^ (sl & 7))] = kbh[c * 2048 + fi];
    }
    __syncthreads();
    float4 a0[4] = {}, a1[4] = {};
#pragma unroll
    for (int d0 = 0; d0 < 16; ++d0) {
      float4 q0 = sQ[n0][d0];
      float4 q1 = sQ[n1][d0];
      int slot2 = d0 ^ (g & 7);
#pragma unroll
      for (int u = 0; u < 4; ++u) {
        float4 kv = sK[(g + 32 * u) * 16 + slot2];
        a0[u].x += q0.x * kv.x; a0[u].y += q0.y * kv.y;
        a0[u].z += q0.z * kv.z; a0[u].w += q0.w * kv.w;
        a1[u].x += q1.x * kv.x; a1[u].y += q1.y * kv.y;
        a1[u].z += q1.z * kv.z; a1[u].w += q1.w * kv.w;
      }
    }
#pragma unroll
    for (int u = 0; u < 4; ++u) {
      int s = c * 128 + g + 32 * u;
      p[n0][s] = a0[u].x + a0[u].y + a0[u].z + a0[u].w;
      p[n1][s] = a1[u].x + a1[u].y + a1[u].z + a1[u].w;
    }
  }
  __syncthreads();

  // ---- softmax per row; activity = 1/sum ----
  {
    int n = t >> 4, sub = t & 15;
    float m = -1e30f;
#pragma unroll 8
    for (int u = 0; u < 64; ++u) m = fmaxf(m, p[n][sub + 16 * u]);
    m = fmaxf(m, __shfl_xor(m, 1)); m = fmaxf(m, __shfl_xor(m, 2));
    m = fmaxf(m, __shfl_xor(m, 4)); m = fmaxf(m, __shfl_xor(m, 8));
    float sum = 0.f;
#pragma unroll 8
    for (int u = 0; u < 64; ++u) {
      float e = __expf(p[n][sub + 16 * u] - m);
      p[n][sub + 16 * u] = e;
      sum += e;
    }
    sum += __shfl_xor(sum, 1); sum += __shfl_xor(sum, 2);
    sum += __shfl_xor(sum, 4); sum += __shfl_xor(sum, 8);
    if (sub == 0) {
      float inv = 1.0f / sum;
      linv[n] = inv;
      invsum[(b * 12 + h) * 128 + ng * 16 + n] = inv;
    }
  }

  // ---- PV ----
  const int dq = t & 15, nq = (t >> 4) & 3, sq = t >> 6;
  float4 acc[4] = {};
  for (int c = 0; c < 8; ++c) {
    __syncthreads();
#pragma unroll
    for (int w = 0; w < 8; ++w) {
      int fi = w * 256 + t;
      int sl = fi >> 4, dqq = fi & 15;
      sK[sl * 16 + (dqq ^ (sl & 7))] = vbh[c * 2048 + fi];
    }
    __syncthreads();
#pragma unroll 2
    for (int v4 = 0; v4 < 32; v4 += 4) {
      int sl0 = sq * 32 + v4;
      int s0 = c * 128 + sl0;
      float pr[4][4];
#pragma unroll
      for (int i = 0; i < 4; ++i)
        *(float4*)&pr[i][0] = *(const float4*)&p[nq * 4 + i][s0];
#pragma unroll
      for (int u = 0; u < 4; ++u) {
        int sl = sl0 + u;
        float4 vv = sK[sl * 16 + (dq ^ (sl & 7))];
#pragma unroll
        for (int i = 0; i < 4; ++i) {
          float pw = pr[i][u];
          acc[i].x += pw * vv.x; acc[i].y += pw * vv.y;
          acc[i].z += pw * vv.z; acc[i].w += pw * vv.w;
        }
      }
    }
  }
#pragma unroll
  for (int i = 0; i < 4; ++i) part[sq][nq][i][dq] = acc[i];
  __syncthreads();
  {
    int n = t >> 4, dqq = t & 15;
    float4 r0 = part[0][n >> 2][n & 3][dqq];
    float4 r1 = part[1][n >> 2][n & 3][dqq];
    float4 r2 = part[2][n >> 2][n & 3][dqq];
    float4 r3 = part[3][n >> 2][n & 3][dqq];
    float inv = linv[n];
    float4 o;
    o.x = (r0.x + r1.x + r2.x + r3.x) * inv;
    o.y = (r0.y + r1.y + r2.y + r3.y) * inv;
    o.z = (r0.z + r1.z + r2.z + r3.z) * inv;
    o.w = (r0.w + r1.w + r2.w + r3.w) * inv;
    *(float4*)&ctx[(size_t)(b * 128 + ng * 16 + n) * 768 + h * 64 + dqq * 4] = o;
  }
}

// ---------------------------------------------------------------- entity mask
__global__ void mask_kernel(const float* __restrict__ invsum,
                            float* __restrict__ mask_out) {
  int t = threadIdx.x;                   // 512 = B*N
  int b = t >> 7, n = t & 127;
  float a = 0.f;
  for (int h = 0; h < 12; ++h) a = fmaxf(a, invsum[(b * 12 + h) * 128 + n]);
  mask_out[t] = (a > 0.001f) ? 1.0f : 0.0f;
}

// ---------------------------------------------------------------- masked entities out
__global__ __launch_bounds__(256) void entmask_kernel(
    const float* __restrict__ ent, const float* __restrict__ mask,
    float* __restrict__ out) {
  int bi = blockIdx.x;                   // b*128+i
  float m = mask[bi];
  for (int e = threadIdx.x; e < 768; e += 256)
    out[(size_t)bi * 768 + e] = ent[(size_t)bi * 768 + e] * m;
}

// ---------------------------------------------------------------- fused edge refinement + gate + mask
__global__ __launch_bounds__(256) void refine_kernel(
    const float* __restrict__ A1, const float* __restrict__ B1,
    const float* __restrict__ C1, const float* __restrict__ w1g,
    const float* __restrict__ W2, const float* __restrict__ b2,
    const float* __restrict__ Ag, const float* __restrict__ Bg,
    const float* __restrict__ Wg2, const float* __restrict__ bg2,
    const float* __restrict__ graph_init, const float* __restrict__ mask,
    float* __restrict__ graph_out) {
  const int bi = blockIdx.x >> 2;        // b*128 + i
  const int jq = blockIdx.x & 3;         // j-quarter
  const int b = bi >> 7;
  const int lane = threadIdx.x & 63, wv = threadIdx.x >> 6;

  float base[12], w1gr[12], w2r[12], agr[12], wg2r[12];
#pragma unroll
  for (int r = 0; r < 12; ++r) {
    int e = r * 64 + lane;
    base[r] = A1[(size_t)bi * 768 + e] + C1[b * 768 + e];
    w1gr[r] = w1g[e];
    w2r[r]  = W2[e];
    agr[r]  = Ag[(size_t)bi * 768 + e];
    wg2r[r] = Wg2[e];
  }
  const float b2s = b2[0], bg2s = bg2[0];
  const float mi = mask[bi];

  const int jend = jq * 32 + 32;
  for (int j = jq * 32 + wv; j < jend; j += 4) {
    float g = graph_init[(size_t)bi * 128 + j] * 1.6f - 0.8f;
    const float* B1j = &B1[((size_t)(b * NE + j)) * 768 + lane];
    const float* Bgj = &Bg[((size_t)(b * NE + j)) * 768 + lane];
    float pre[12], gpre[12];
#pragma unroll
    for (int r = 0; r < 12; ++r) {
      pre[r]  = base[r] + B1j[r * 64];
      gpre[r] = agr[r] + Bgj[r * 64];
    }
#pragma unroll
    for (int st = 0; st < 3; ++st) {
      float acc = 0.f;
#pragma unroll
      for (int r = 0; r < 12; ++r) {
        float hx = pre[r] + g * w1gr[r];
        acc += gelu_fast(hx) * w2r[r];
      }
      acc += __shfl_xor(acc, 1);  acc += __shfl_xor(acc, 2);
      acc += __shfl_xor(acc, 4);  acc += __shfl_xor(acc, 8);
      acc += __shfl_xor(acc, 16); acc += __shfl_xor(acc, 32);
      g += tanh_fast(acc + b2s);
    }
    float gacc = 0.f;
#pragma unroll
    for (int r = 0; r < 12; ++r) gacc += gelu_fast(gpre[r]) * wg2r[r];
    gacc += __shfl_xor(gacc, 1);  gacc += __shfl_xor(gacc, 2);
    gacc += __shfl_xor(gacc, 4);  gacc += __shfl_xor(gacc, 8);
    gacc += __shfl_xor(gacc, 16); gacc += __shfl_xor(gacc, 32);
    float gate = sigmoid_fast(gacc + bg2s);
    if (lane == 0)
      graph_out[(size_t)bi * 128 + j] = g * gate * mi * mask[b * NE + j];
  }
}

}  // namespace

extern "C" void kernel_launch(void* const* d_in, const int* in_sizes, int n_in,
                              void* d_out, int out_size, void* d_ws, size_t ws_size,
                              hipStream_t stream) {
  const float* emb  = (const float*)d_in[0];
  const float* ginit= (const float*)d_in[1];
  const float* lib  = (const float*)d_in[2];
  const float* pos  = (const float*)d_in[3];
  const float* Wq   = (const float*)d_in[4];
  const float* bq   = (const float*)d_in[5];
  const float* Wk   = (const float*)d_in[6];
  const float* bk   = (const float*)d_in[7];
  const float* Wv   = (const float*)d_in[8];
  const float* bv   = (const float*)d_in[9];
  const float* Wo   = (const float*)d_in[10];
  const float* bo   = (const float*)d_in[11];
  const float* W1   = (const float*)d_in[12];
  const float* b1   = (const float*)d_in[13];
  const float* W2   = (const float*)d_in[14];
  const float* b2   = (const float*)d_in[15];
  const float* Wg1  = (const float*)d_in[16];
  const float* bg1  = (const float*)d_in[17];
  const float* Wg2  = (const float*)d_in[18];
  const float* bg2  = (const float*)d_in[19];

  float* ws = (float*)d_ws;
  float* k2   = ws + 0;                 // (B,H,S,64)  3,145,728
  float* v2   = ws + 3145728;           // (B,H,S,64)  3,145,728
  float* x_   = ws + 6291456;           // 3,145,728 (dead after kv/ctxmean)
  float* A1   = ws + 6291456;           // reuse x space (zeroed after kv)
  float* B1   = ws + 6684672;
  float* Ag   = ws + 7077888;
  float* Bg   = ws + 7471104;           // ends 7864320
  float* q_   = ws + 9437184;           // 98,304
  float* ctx_ = ws + 9535488;           // 393,216
  float* ent_ = ws + 9928704;           // 393,216
  float* ctxv = ws + 10321920;          // 3,072
  float* C1   = ws + 10324992;          // 3,072
  float* invs = ws + 10328064;          // 6,144

  float* out_ent   = (float*)d_out;           // 393,216
  float* out_graph = out_ent + 393216;        // 65,536
  float* out_mask  = out_ent + 458752;        // 512

  // 0. zero atomic-accumulation targets: k2+v2, and q_..ent_ span
  zero_kernel<<<6144, 256, 0, stream>>>((float4*)k2);
  zero_kernel<<<864, 256, 0, stream>>>((float4*)q_);
  // 1. x = emb + pos
  posadd_kernel<<<3072, 256, 0, stream>>>(emb, pos, x_);
  // 2. context = mean_s x
  ctxmean_kernel<<<48, 256, 0, stream>>>(x_, ctxv);
  // 3. q = lib @ Wq + bq (split-K x8)
  {
    GemmSet gq; gq.W[0] = Wq; gq.bias[0] = bq; gq.C[0] = q_;
    gemm_splitk_kernel<<<dim3(1, 6, 8), 256, 0, stream>>>(lib, gq, 8, 96);
  }
  // 4. k2/v2 = x @ Wk/Wv + b, transposed to (B,H,S,64); 768 blocks = 3/CU
  kv_gemm_kernel<<<dim3(32, 12, 2), 256, 0, stream>>>(x_, Wk, bk, Wv, bv, k2, v2);
  // 5. attention -> ctx (B,N,H*K), invsum (B,H,N)
  attn2_kernel<<<384, 256, 0, stream>>>(q_, k2, v2, ctx_, invs);
  // 6. entity mask
  mask_kernel<<<1, 512, 0, stream>>>(invs, out_mask);
  // 7. entities = ctx @ Wo + bo (split-K x16)
  {
    GemmSet go; go.W[0] = Wo; go.bias[0] = bo; go.C[0] = ent_;
    gemm_splitk_kernel<<<dim3(4, 6, 16), 256, 0, stream>>>(ctx_, go, 16, 48);
  }
  // 8. masked entities out
  entmask_kernel<<<512, 256, 0, stream>>>(ent_, out_mask, out_ent);
  // 9. zero A1..Bg (x_ now dead), then fused projections (split-K x8, 4 mats)
  zero_kernel<<<1536, 256, 0, stream>>>((float4*)A1);
  {
    GemmSet gp;
    gp.W[0] = W1;           gp.bias[0] = nullptr; gp.C[0] = A1;
    gp.W[1] = W1 + 589824;  gp.bias[1] = nullptr; gp.C[1] = B1;
    gp.W[2] = Wg1;          gp.bias[2] = bg1;     gp.C[2] = Ag;
    gp.W[3] = Wg1 + 589824; gp.bias[3] = nullptr; gp.C[3] = Bg;
    gemm_splitk_kernel<<<dim3(4, 6, 32), 256, 0, stream>>>(ent_, gp, 8, 96);
  }
  // 10. C1 = context @ W1d + b1
  gemm768_kernel<<<dim3(1, 12), 256, 0, stream>>>(ctxv, W1 + 1537 * 768, b1, C1, 4);
  // 11. fused edge refinement (3 steps) + gate + entity masking
  refine_kernel<<<2048, 256, 0, stream>>>(A1, B1, C1, W1 + 1536 * 768, W2, b2,
                                          Ag, Bg, Wg2, bg2, ginit, out_mask,
                                          out_graph);
}

// Round 6
// 696.421 us; speedup vs baseline: 1.4108x; 1.4108x over previous
//
#include <hip/hip_runtime.h>
#include <hip/hip_bf16.h>
#include <math.h>

namespace {
constexpr int SEQ  = 1024;
constexpr int NE   = 128;

__device__ __forceinline__ float rcp_fast(float x) {
  return __builtin_amdgcn_rcpf(x);
}

__device__ __forceinline__ float gelu_fast(float x) {
  float x2 = x * x;
  float t = fmaf(x2, -0.1029443f, -2.3022093f);
  return x * rcp_fast(1.0f + exp2f(x * t));
}

__device__ __forceinline__ float tanh_fast(float x) {
  return 1.0f - 2.0f * rcp_fast(1.0f + exp2f(x * 2.8853901f));
}

__device__ __forceinline__ float sigmoid_fast(float x) {
  return rcp_fast(1.0f + exp2f(x * -1.4426950f));
}

// ---------------------------------------------------------------- pos add
__global__ __launch_bounds__(256) void posadd_kernel(
    const float* __restrict__ emb, const float* __restrict__ pos,
    float* __restrict__ x) {
  int i = blockIdx.x * 256 + threadIdx.x;      // float4 index; total 786432
  const int perB = SEQ * 768 / 4;              // 196608
  int pi = i - (i / perB) * perB;
  float4 e4 = ((const float4*)emb)[i];
  float4 p4 = ((const float4*)pos)[pi];
  e4.x += p4.x; e4.y += p4.y; e4.z += p4.z; e4.w += p4.w;
  ((float4*)x)[i] = e4;
}

// ---------------------------------------------------------------- context mean
__global__ __launch_bounds__(256) void ctxmean_kernel(
    const float* __restrict__ x, float* __restrict__ ctxv) {
  int b = blockIdx.x / 12, chunk = blockIdx.x % 12;
  int lane = threadIdx.x & 63, sg = threadIdx.x >> 6;
  int d = chunk * 64 + lane;
  float acc = 0.f;
  const float* xb = x + ((size_t)b * SEQ + sg) * 768 + d;
  for (int s = sg; s < SEQ; s += 4) { acc += *xb; xb += 4 * 768; }
  __shared__ float red[4][64];
  red[sg][lane] = acc;
  __syncthreads();
  if (threadIdx.x < 64) {
    float t = red[0][threadIdx.x] + red[1][threadIdx.x] +
              red[2][threadIdx.x] + red[3][threadIdx.x];
    ctxv[b * 768 + chunk * 64 + threadIdx.x] = t * (1.0f / 1024.0f);
  }
}

// ---------------------------------------------------------------- small GEMM  C[Mx768] = A[Mx768] @ W[768x768] (+bias)
__global__ __launch_bounds__(256) void gemm768_kernel(
    const float* __restrict__ A, const float* __restrict__ W,
    const float* __restrict__ bias, float* __restrict__ C, int M) {
  __shared__ __align__(16) float sA[16][68];
  __shared__ __align__(16) float sB[16][68];
  const int bm = blockIdx.x * 64;
  const int bn = blockIdx.y * 64;
  const int tid = threadIdx.x;
  const int tm = (tid >> 4) * 4;
  const int tn = (tid & 15) * 4;
  const int lm = tid >> 2, lkq = (tid & 3) * 4;
  const int lkk = tid >> 4, lnq = (tid & 15) * 4;
  float acc[4][4] = {};
  for (int k0 = 0; k0 < 768; k0 += 16) {
    float4 av = make_float4(0.f, 0.f, 0.f, 0.f);
    if (bm + lm < M) av = *(const float4*)&A[(size_t)(bm + lm) * 768 + k0 + lkq];
    float4 wv = *(const float4*)&W[(size_t)(k0 + lkk) * 768 + bn + lnq];
    __syncthreads();
    sA[lkq + 0][lm] = av.x; sA[lkq + 1][lm] = av.y;
    sA[lkq + 2][lm] = av.z; sA[lkq + 3][lm] = av.w;
    *(float4*)&sB[lkk][lnq] = wv;
    __syncthreads();
#pragma unroll
    for (int kk = 0; kk < 16; ++kk) {
      float4 a = *(const float4*)&sA[kk][tm];
      float4 w = *(const float4*)&sB[kk][tn];
      acc[0][0] += a.x * w.x; acc[0][1] += a.x * w.y; acc[0][2] += a.x * w.z; acc[0][3] += a.x * w.w;
      acc[1][0] += a.y * w.x; acc[1][1] += a.y * w.y; acc[1][2] += a.y * w.z; acc[1][3] += a.y * w.w;
      acc[2][0] += a.z * w.x; acc[2][1] += a.z * w.y; acc[2][2] += a.z * w.z; acc[2][3] += a.z * w.w;
      acc[3][0] += a.w * w.x; acc[3][1] += a.w * w.y; acc[3][2] += a.w * w.z; acc[3][3] += a.w * w.w;
    }
  }
#pragma unroll
  for (int i = 0; i < 4; ++i) {
    int row = bm + tm + i;
    if (row < M) {
#pragma unroll
      for (int j = 0; j < 4; ++j) {
        float o = acc[i][j];
        if (bias) o += bias[bn + tn + j];
        C[(size_t)row * 768 + bn + tn + j] = o;
      }
    }
  }
}

// ---------------------------------------------------------------- 4-way fused projection GEMM (shared A, M=512)
struct ProjParams {
  const float* W[4];
  const float* bias[4];
  float* C[4];
};

__global__ __launch_bounds__(256) void gemm768x4_kernel(
    const float* __restrict__ A, ProjParams pp) {
  __shared__ __align__(16) float sA[16][68];
  __shared__ __align__(16) float sB[16][68];
  const int sel = blockIdx.y / 12;
  const float* W = pp.W[sel];
  const float* bias = pp.bias[sel];
  float* C = pp.C[sel];
  const int bm = blockIdx.x * 64;
  const int bn = (blockIdx.y % 12) * 64;
  const int tid = threadIdx.x;
  const int tm = (tid >> 4) * 4;
  const int tn = (tid & 15) * 4;
  const int lm = tid >> 2, lkq = (tid & 3) * 4;
  const int lkk = tid >> 4, lnq = (tid & 15) * 4;
  float acc[4][4] = {};
  for (int k0 = 0; k0 < 768; k0 += 16) {
    float4 av = *(const float4*)&A[(size_t)(bm + lm) * 768 + k0 + lkq];
    float4 wv = *(const float4*)&W[(size_t)(k0 + lkk) * 768 + bn + lnq];
    __syncthreads();
    sA[lkq + 0][lm] = av.x; sA[lkq + 1][lm] = av.y;
    sA[lkq + 2][lm] = av.z; sA[lkq + 3][lm] = av.w;
    *(float4*)&sB[lkk][lnq] = wv;
    __syncthreads();
#pragma unroll
    for (int kk = 0; kk < 16; ++kk) {
      float4 a = *(const float4*)&sA[kk][tm];
      float4 w = *(const float4*)&sB[kk][tn];
      acc[0][0] += a.x * w.x; acc[0][1] += a.x * w.y; acc[0][2] += a.x * w.z; acc[0][3] += a.x * w.w;
      acc[1][0] += a.y * w.x; acc[1][1] += a.y * w.y; acc[1][2] += a.y * w.z; acc[1][3] += a.y * w.w;
      acc[2][0] += a.z * w.x; acc[2][1] += a.z * w.y; acc[2][2] += a.z * w.z; acc[2][3] += a.z * w.w;
      acc[3][0] += a.w * w.x; acc[3][1] += a.w * w.y; acc[3][2] += a.w * w.z; acc[3][3] += a.w * w.w;
    }
  }
#pragma unroll
  for (int i = 0; i < 4; ++i) {
    int row = bm + tm + i;
#pragma unroll
    for (int j = 0; j < 4; ++j) {
      float o = acc[i][j];
      if (bias) o += bias[bn + tn + j];
      C[(size_t)row * 768 + bn + tn + j] = o;
    }
  }
}

// ---------------------------------------------------------------- fused K+V GEMM, 64x128 tile, 4x8 micro, 256 threads
// grid (64, 12) = 768 blocks = 3/CU balanced; direct transposed (B,H,S,64) stores
__global__ __launch_bounds__(256) void kv_gemm_kernel(
    const float* __restrict__ A,
    const float* __restrict__ Wk, const float* __restrict__ bk,
    const float* __restrict__ Wv, const float* __restrict__ bv,
    float* __restrict__ k2, float* __restrict__ v2) {
  __shared__ __align__(16) float sA[16][68];
  __shared__ __align__(16) float sB[16][132];
  const int bm = blockIdx.x * 64;            // 64 rows of 4096
  const bool isV = blockIdx.y >= 6;
  const int bn = (blockIdx.y % 6) * 128;     // 2 heads
  const float* __restrict__ W = isV ? Wv : Wk;
  const float* __restrict__ bias = isV ? bv : bk;
  float* __restrict__ out = isV ? v2 : k2;
  const int t = threadIdx.x;
  const int ar = t >> 2, akq = (t & 3) * 4;  // A loader: 1 float4, 64 rows x 16k
  const int bkr = t >> 4, bq0 = (t & 15) * 4;// W loader: 2 split-col float4
  const int ty = t >> 4, tx = t & 15;        // 4 rows x (4+4) cols

  const float* __restrict__ Ap = A + (size_t)(bm + ar) * 768 + akq;
  const float* __restrict__ Wp = W + (size_t)bkr * 768 + bn + bq0;

  float4 av = *(const float4*)(Ap);
  float4 w0 = *(const float4*)(Wp);
  float4 w1 = *(const float4*)(Wp + 64);

  float acc[4][8] = {};
  for (int k0 = 0; k0 < 768; k0 += 16) {
    __syncthreads();
    sA[akq + 0][ar] = av.x; sA[akq + 1][ar] = av.y;
    sA[akq + 2][ar] = av.z; sA[akq + 3][ar] = av.w;
    *(float4*)&sB[bkr][bq0]      = w0;       // split-col: 2-way bank alias, free
    *(float4*)&sB[bkr][bq0 + 64] = w1;
    __syncthreads();
    if (k0 + 16 < 768) {     // register prefetch of next k-slice
      av = *(const float4*)(Ap + k0 + 16);
      const float* wr = Wp + (size_t)(k0 + 16) * 768;
      w0 = *(const float4*)(wr);
      w1 = *(const float4*)(wr + 64);
    }
#pragma unroll
    for (int kk = 0; kk < 16; ++kk) {
      float4 a  = *(const float4*)&sA[kk][ty * 4];        // broadcast per 16-lane group
      float4 y0 = *(const float4*)&sB[kk][tx * 4];        // 2-way alias, free
      float4 y1 = *(const float4*)&sB[kk][64 + tx * 4];
      float xa[4] = {a.x, a.y, a.z, a.w};
      float yb[8] = {y0.x, y0.y, y0.z, y0.w, y1.x, y1.y, y1.z, y1.w};
#pragma unroll
      for (int i = 0; i < 4; ++i)
#pragma unroll
        for (int j = 0; j < 8; ++j)
          acc[i][j] += xa[i] * yb[j];
    }
  }

  const int bidx = bm >> 10;
  const int s_base = bm & 1023;
  const int h0 = bn >> 6;
  float bs0[4], bs1[4];
#pragma unroll
  for (int j = 0; j < 4; ++j) {
    bs0[j] = bias[bn + tx * 4 + j];
    bs1[j] = bias[bn + 64 + tx * 4 + j];
  }
#pragma unroll
  for (int i = 0; i < 4; ++i) {
    int s = s_base + ty * 4 + i;
    float4 o0 = make_float4(acc[i][0] + bs0[0], acc[i][1] + bs0[1],
                            acc[i][2] + bs0[2], acc[i][3] + bs0[3]);
    float4 o1 = make_float4(acc[i][4] + bs1[0], acc[i][5] + bs1[1],
                            acc[i][6] + bs1[2], acc[i][7] + bs1[3]);
    *(float4*)&out[(((size_t)(bidx * 12 + h0)) * 1024 + s) * 64 + tx * 4] = o0;
    *(float4*)&out[(((size_t)(bidx * 12 + h0 + 1)) * 1024 + s) * 64 + tx * 4] = o1;
  }
}

// ---------------------------------------------------------------- flash-style attention, 16 queries/block, (B,H,S,64) K/V
__global__ __launch_bounds__(256) void attn2_kernel(
    const float* __restrict__ q, const float* __restrict__ k2,
    const float* __restrict__ v2, float* __restrict__ ctx,
    float* __restrict__ invsum) {
  __shared__ float p[16][1028];
  __shared__ float4 sK[128 * 16];         // swizzled: [s][dq ^ (s&7)]
  __shared__ float4 sQ[16][16];
  __shared__ float linv[16];
  __shared__ float4 part[4][4][4][16];    // [sq][nq][i][dq]

  // XCD-aware remap: one (b,h)'s 8 q-group blocks land on one XCD
  const int xcd = blockIdx.x & 7;
  const int slot = blockIdx.x >> 3;       // 0..47
  const int bh = xcd * 6 + (slot >> 3);   // 0..47
  const int ng = slot & 7;
  const int b = bh / 12, h = bh % 12;
  const int t = threadIdx.x;

  {  // stage Q, fold 1/sqrt(64)
    int nn = t >> 4, dq = t & 15;
    float4 qv = *(const float4*)&q[(size_t)(ng * 16 + nn) * 768 + h * 64 + dq * 4];
    qv.x *= 0.125f; qv.y *= 0.125f; qv.z *= 0.125f; qv.w *= 0.125f;
    sQ[nn][dq] = qv;
  }
  const float4* kbh = (const float4*)(k2 + ((size_t)(b * 12 + h)) * 1024 * 64);
  const float4* vbh = (const float4*)(v2 + ((size_t)(b * 12 + h)) * 1024 * 64);

  const int npair = t >> 5;               // 0..7
  const int g = t & 31;
  const int n0 = npair * 2, n1 = n0 + 1;

  // ---- QK^T into p ----
  for (int c = 0; c < 8; ++c) {
    __syncthreads();
#pragma unroll
    for (int w = 0; w < 8; ++w) {
      int fi = w * 256 + t;
      int sl = fi >> 4, dq = fi & 15;
      sK[sl * 16 + (dq ^ (sl & 7))] = kbh[c * 2048 + fi];
    }
    __syncthreads();
    float4 a0[4] = {}, a1[4] = {};
#pragma unroll
    for (int d0 = 0; d0 < 16; ++d0) {
      float4 q0 = sQ[n0][d0];
      float4 q1 = sQ[n1][d0];
      int slot2 = d0 ^ (g & 7);
#pragma unroll
      for (int u = 0; u < 4; ++u) {
        float4 kv = sK[(g + 32 * u) * 16 + slot2];
        a0[u].x += q0.x * kv.x; a0[u].y += q0.y * kv.y;
        a0[u].z += q0.z * kv.z; a0[u].w += q0.w * kv.w;
        a1[u].x += q1.x * kv.x; a1[u].y += q1.y * kv.y;
        a1[u].z += q1.z * kv.z; a1[u].w += q1.w * kv.w;
      }
    }
#pragma unroll
    for (int u = 0; u < 4; ++u) {
      int s = c * 128 + g + 32 * u;
      p[n0][s] = a0[u].x + a0[u].y + a0[u].z + a0[u].w;
      p[n1][s] = a1[u].x + a1[u].y + a1[u].z + a1[u].w;
    }
  }
  __syncthreads();

  // ---- softmax per row; activity = 1/sum ----
  {
    int n = t >> 4, sub = t & 15;
    float m = -1e30f;
#pragma unroll 8
    for (int u = 0; u < 64; ++u) m = fmaxf(m, p[n][sub + 16 * u]);
    m = fmaxf(m, __shfl_xor(m, 1)); m = fmaxf(m, __shfl_xor(m, 2));
    m = fmaxf(m, __shfl_xor(m, 4)); m = fmaxf(m, __shfl_xor(m, 8));
    float sum = 0.f;
#pragma unroll 8
    for (int u = 0; u < 64; ++u) {
      float e = __expf(p[n][sub + 16 * u] - m);
      p[n][sub + 16 * u] = e;
      sum += e;
    }
    sum += __shfl_xor(sum, 1); sum += __shfl_xor(sum, 2);
    sum += __shfl_xor(sum, 4); sum += __shfl_xor(sum, 8);
    if (sub == 0) {
      float inv = 1.0f / sum;
      linv[n] = inv;
      invsum[(b * 12 + h) * 128 + ng * 16 + n] = inv;
    }
  }

  // ---- PV ----
  const int dq = t & 15, nq = (t >> 4) & 3, sq = t >> 6;
  float4 acc[4] = {};
  for (int c = 0; c < 8; ++c) {
    __syncthreads();
#pragma unroll
    for (int w = 0; w < 8; ++w) {
      int fi = w * 256 + t;
      int sl = fi >> 4, dqq = fi & 15;
      sK[sl * 16 + (dqq ^ (sl & 7))] = vbh[c * 2048 + fi];
    }
    __syncthreads();
#pragma unroll 2
    for (int v4 = 0; v4 < 32; v4 += 4) {
      int sl0 = sq * 32 + v4;
      int s0 = c * 128 + sl0;
      float pr[4][4];
#pragma unroll
      for (int i = 0; i < 4; ++i)
        *(float4*)&pr[i][0] = *(const float4*)&p[nq * 4 + i][s0];
#pragma unroll
      for (int u = 0; u < 4; ++u) {
        int sl = sl0 + u;
        float4 vv = sK[sl * 16 + (dq ^ (sl & 7))];
#pragma unroll
        for (int i = 0; i < 4; ++i) {
          float pw = pr[i][u];
          acc[i].x += pw * vv.x; acc[i].y += pw * vv.y;
          acc[i].z += pw * vv.z; acc[i].w += pw * vv.w;
        }
      }
    }
  }
#pragma unroll
  for (int i = 0; i < 4; ++i) part[sq][nq][i][dq] = acc[i];
  __syncthreads();
  {
    int n = t >> 4, dqq = t & 15;
    float4 r0 = part[0][n >> 2][n & 3][dqq];
    float4 r1 = part[1][n >> 2][n & 3][dqq];
    float4 r2 = part[2][n >> 2][n & 3][dqq];
    float4 r3 = part[3][n >> 2][n & 3][dqq];
    float inv = linv[n];
    float4 o;
    o.x = (r0.x + r1.x + r2.x + r3.x) * inv;
    o.y = (r0.y + r1.y + r2.y + r3.y) * inv;
    o.z = (r0.z + r1.z + r2.z + r3.z) * inv;
    o.w = (r0.w + r1.w + r2.w + r3.w) * inv;
    *(float4*)&ctx[(size_t)(b * 128 + ng * 16 + n) * 768 + h * 64 + dqq * 4] = o;
  }
}

// ---------------------------------------------------------------- entity mask
__global__ void mask_kernel(const float* __restrict__ invsum,
                            float* __restrict__ mask_out) {
  int t = threadIdx.x;                   // 512 = B*N
  int b = t >> 7, n = t & 127;
  float a = 0.f;
  for (int h = 0; h < 12; ++h) a = fmaxf(a, invsum[(b * 12 + h) * 128 + n]);
  mask_out[t] = (a > 0.001f) ? 1.0f : 0.0f;
}

// ---------------------------------------------------------------- masked entities out
__global__ __launch_bounds__(256) void entmask_kernel(
    const float* __restrict__ ent, const float* __restrict__ mask,
    float* __restrict__ out) {
  int bi = blockIdx.x;                   // b*128+i
  float m = mask[bi];
  for (int e = threadIdx.x; e < 768; e += 256)
    out[(size_t)bi * 768 + e] = ent[(size_t)bi * 768 + e] * m;
}

// ---------------------------------------------------------------- fused edge refinement + gate + mask
__global__ __launch_bounds__(256) void refine_kernel(
    const float* __restrict__ A1, const float* __restrict__ B1,
    const float* __restrict__ C1, const float* __restrict__ w1g,
    const float* __restrict__ W2, const float* __restrict__ b2,
    const float* __restrict__ Ag, const float* __restrict__ Bg,
    const float* __restrict__ Wg2, const float* __restrict__ bg2,
    const float* __restrict__ graph_init, const float* __restrict__ mask,
    float* __restrict__ graph_out) {
  const int bi = blockIdx.x >> 2;        // b*128 + i
  const int jq = blockIdx.x & 3;         // j-quarter
  const int b = bi >> 7;
  const int lane = threadIdx.x & 63, wv = threadIdx.x >> 6;

  float base[12], w1gr[12], w2r[12], agr[12], wg2r[12];
#pragma unroll
  for (int r = 0; r < 12; ++r) {
    int e = r * 64 + lane;
    base[r] = A1[(size_t)bi * 768 + e] + C1[b * 768 + e];
    w1gr[r] = w1g[e];
    w2r[r]  = W2[e];
    agr[r]  = Ag[(size_t)bi * 768 + e];
    wg2r[r] = Wg2[e];
  }
  const float b2s = b2[0], bg2s = bg2[0];
  const float mi = mask[bi];

  const int jend = jq * 32 + 32;
  for (int j = jq * 32 + wv; j < jend; j += 4) {
    float g = graph_init[(size_t)bi * 128 + j] * 1.6f - 0.8f;
    const float* B1j = &B1[((size_t)(b * NE + j)) * 768 + lane];
    const float* Bgj = &Bg[((size_t)(b * NE + j)) * 768 + lane];
    float pre[12], gpre[12];
#pragma unroll
    for (int r = 0; r < 12; ++r) {
      pre[r]  = base[r] + B1j[r * 64];
      gpre[r] = agr[r] + Bgj[r * 64];
    }
#pragma unroll
    for (int st = 0; st < 3; ++st) {
      float acc = 0.f;
#pragma unroll
      for (int r = 0; r < 12; ++r) {
        float hx = pre[r] + g * w1gr[r];
        acc += gelu_fast(hx) * w2r[r];
      }
      acc += __shfl_xor(acc, 1);  acc += __shfl_xor(acc, 2);
      acc += __shfl_xor(acc, 4);  acc += __shfl_xor(acc, 8);
      acc += __shfl_xor(acc, 16); acc += __shfl_xor(acc, 32);
      g += tanh_fast(acc + b2s);
    }
    float gacc = 0.f;
#pragma unroll
    for (int r = 0; r < 12; ++r) gacc += gelu_fast(gpre[r]) * wg2r[r];
    gacc += __shfl_xor(gacc, 1);  gacc += __shfl_xor(gacc, 2);
    gacc += __shfl_xor(gacc, 4);  gacc += __shfl_xor(gacc, 8);
    gacc += __shfl_xor(gacc, 16); gacc += __shfl_xor(gacc, 32);
    float gate = sigmoid_fast(gacc + bg2s);
    if (lane == 0)
      graph_out[(size_t)bi * 128 + j] = g * gate * mi * mask[b * NE + j];
  }
}

}  // namespace

extern "C" void kernel_launch(void* const* d_in, const int* in_sizes, int n_in,
                              void* d_out, int out_size, void* d_ws, size_t ws_size,
                              hipStream_t stream) {
  const float* emb  = (const float*)d_in[0];
  const float* ginit= (const float*)d_in[1];
  const float* lib  = (const float*)d_in[2];
  const float* pos  = (const float*)d_in[3];
  const float* Wq   = (const float*)d_in[4];
  const float* bq   = (const float*)d_in[5];
  const float* Wk   = (const float*)d_in[6];
  const float* bk   = (const float*)d_in[7];
  const float* Wv   = (const float*)d_in[8];
  const float* bv   = (const float*)d_in[9];
  const float* Wo   = (const float*)d_in[10];
  const float* bo   = (const float*)d_in[11];
  const float* W1   = (const float*)d_in[12];
  const float* b1   = (const float*)d_in[13];
  const float* W2   = (const float*)d_in[14];
  const float* b2   = (const float*)d_in[15];
  const float* Wg1  = (const float*)d_in[16];
  const float* bg1  = (const float*)d_in[17];
  const float* Wg2  = (const float*)d_in[18];
  const float* bg2  = (const float*)d_in[19];

  float* ws = (float*)d_ws;
  float* k2   = ws + 0;                 // (B,H,S,64)  3,145,728
  float* v2   = ws + 3145728;           // (B,H,S,64)  3,145,728
  float* x_   = ws + 6291456;           // 3,145,728 (dead after kv/ctxmean)
  float* A1   = ws + 6291456;           // reuse x space after kv
  float* B1   = ws + 6684672;
  float* Ag   = ws + 7077888;
  float* Bg   = ws + 7471104;           // ends 7864320
  float* q_   = ws + 9437184;           // 98,304
  float* ctx_ = ws + 9535488;           // 393,216
  float* ent_ = ws + 9928704;           // 393,216
  float* ctxv = ws + 10321920;          // 3,072
  float* C1   = ws + 10324992;          // 3,072
  float* invs = ws + 10328064;          // 6,144

  float* out_ent   = (float*)d_out;           // 393,216
  float* out_graph = out_ent + 393216;        // 65,536
  float* out_mask  = out_ent + 458752;        // 512

  // 1. x = emb + pos
  posadd_kernel<<<3072, 256, 0, stream>>>(emb, pos, x_);
  // 2. context = mean_s x
  ctxmean_kernel<<<48, 256, 0, stream>>>(x_, ctxv);
  // 3. q = lib @ Wq + bq
  gemm768_kernel<<<dim3(2, 12), 256, 0, stream>>>(lib, Wq, bq, q_, 128);
  // 4. k2/v2 = x @ Wk/Wv + b, transposed to (B,H,S,64); 768 blocks = 3/CU
  kv_gemm_kernel<<<dim3(64, 12), 256, 0, stream>>>(x_, Wk, bk, Wv, bv, k2, v2);
  // 5. attention -> ctx (B,N,H*K), invsum (B,H,N)
  attn2_kernel<<<384, 256, 0, stream>>>(q_, k2, v2, ctx_, invs);
  // 6. entity mask
  mask_kernel<<<1, 512, 0, stream>>>(invs, out_mask);
  // 7. entities = ctx @ Wo + bo
  gemm768_kernel<<<dim3(8, 12), 256, 0, stream>>>(ctx_, Wo, bo, ent_, 512);
  // 8. masked entities out
  entmask_kernel<<<512, 256, 0, stream>>>(ent_, out_mask, out_ent);
  // 9. fused per-entity projections for edge MLPs (A1,B1,Ag,Bg)
  ProjParams pp;
  pp.W[0] = W1;              pp.bias[0] = nullptr; pp.C[0] = A1;
  pp.W[1] = W1 + 589824;     pp.bias[1] = nullptr; pp.C[1] = B1;
  pp.W[2] = Wg1;             pp.bias[2] = bg1;     pp.C[2] = Ag;
  pp.W[3] = Wg1 + 589824;    pp.bias[3] = nullptr; pp.C[3] = Bg;
  gemm768x4_kernel<<<dim3(8, 48), 256, 0, stream>>>(ent_, pp);
  // 10. C1 = context @ W1d + b1
  gemm768_kernel<<<dim3(1, 12), 256, 0, stream>>>(ctxv, W1 + 1537 * 768, b1, C1, 4);
  // 11. fused edge refinement (3 steps) + gate + entity masking
  refine_kernel<<<2048, 256, 0, stream>>>(A1, B1, C1, W1 + 1536 * 768, W2, b2,
                                          Ag, Bg, Wg2, bg2, ginit, out_mask,
                                          out_graph);
}

// Round 7
// 618.094 us; speedup vs baseline: 1.5896x; 1.1267x over previous
//
#include <hip/hip_runtime.h>
#include <hip/hip_bf16.h>
#include <math.h>

namespace {
constexpr int SEQ  = 1024;
constexpr int NE   = 128;

typedef float f32x4  __attribute__((ext_vector_type(4)));
typedef short bf16x8 __attribute__((ext_vector_type(8)));

__device__ __forceinline__ float rcp_fast(float x) {
  return __builtin_amdgcn_rcpf(x);
}

__device__ __forceinline__ float gelu_fast(float x) {
  float x2 = x * x;
  float t = fmaf(x2, -0.1029443f, -2.3022093f);
  return x * rcp_fast(1.0f + exp2f(x * t));
}

__device__ __forceinline__ float tanh_fast(float x) {
  return 1.0f - 2.0f * rcp_fast(1.0f + exp2f(x * 2.8853901f));
}

__device__ __forceinline__ float sigmoid_fast(float x) {
  return rcp_fast(1.0f + exp2f(x * -1.4426950f));
}

__device__ __forceinline__ ushort f2bf(float f) {
  union { float f; unsigned u; } c; c.f = f;
  unsigned u = c.u;
  u += 0x7FFF + ((u >> 16) & 1);            // RNE
  return (ushort)(u >> 16);
}

// ---------------------------------------------------------------- pos add -> bf16 x
__global__ __launch_bounds__(256) void posadd_bf16_kernel(
    const float* __restrict__ emb, const float* __restrict__ pos,
    ushort* __restrict__ xb) {
  int i = blockIdx.x * 256 + threadIdx.x;      // 8-float chunk; total 393216
  const int perB = SEQ * 768 / 8;              // 98304
  int pi = i - (i / perB) * perB;
  float4 e0 = ((const float4*)emb)[i * 2];
  float4 e1 = ((const float4*)emb)[i * 2 + 1];
  float4 p0 = ((const float4*)pos)[pi * 2];
  float4 p1 = ((const float4*)pos)[pi * 2 + 1];
  ushort o[8];
  o[0] = f2bf(e0.x + p0.x); o[1] = f2bf(e0.y + p0.y);
  o[2] = f2bf(e0.z + p0.z); o[3] = f2bf(e0.w + p0.w);
  o[4] = f2bf(e1.x + p1.x); o[5] = f2bf(e1.y + p1.y);
  o[6] = f2bf(e1.z + p1.z); o[7] = f2bf(e1.w + p1.w);
  *(uint4*)&xb[(size_t)i * 8] = *(uint4*)o;
}

// ---------------------------------------------------------------- weight transpose-convert: W[k][n] f32 -> Wt[n][k] bf16
__global__ __launch_bounds__(256) void wconv_kernel(
    const float* __restrict__ Wk, const float* __restrict__ Wv,
    ushort* __restrict__ WtK, ushort* __restrict__ WtV) {
  const float* __restrict__ W  = blockIdx.z ? Wv : Wk;
  ushort* __restrict__ Wt = blockIdx.z ? WtV : WtK;
  const int k0 = blockIdx.x * 64, n0 = blockIdx.y * 64;
  __shared__ ushort sT[64][72];               // [n][k], padded
  const int t = threadIdx.x;
  const int rr = t >> 4, c4 = (t & 15) * 4;
#pragma unroll
  for (int i = 0; i < 4; ++i) {
    int r = rr + 16 * i;
    float4 v = *(const float4*)&W[(size_t)(k0 + r) * 768 + n0 + c4];
    sT[c4 + 0][r] = f2bf(v.x);
    sT[c4 + 1][r] = f2bf(v.y);
    sT[c4 + 2][r] = f2bf(v.z);
    sT[c4 + 3][r] = f2bf(v.w);
  }
  __syncthreads();
#pragma unroll
  for (int j = 0; j < 2; ++j) {
    int cid = t + 256 * j;
    int nr = cid >> 3, kc8 = (cid & 7) * 8;
    *(uint4*)&Wt[(size_t)(n0 + nr) * 768 + k0 + kc8] = *(uint4*)&sT[nr][kc8];
  }
}

// ---------------------------------------------------------------- context mean (from emb+pos directly)
__global__ __launch_bounds__(256) void ctxmean_kernel(
    const float* __restrict__ emb, const float* __restrict__ pos,
    float* __restrict__ ctxv) {
  int b = blockIdx.x / 12, chunk = blockIdx.x % 12;
  int lane = threadIdx.x & 63, sg = threadIdx.x >> 6;
  int d = chunk * 64 + lane;
  float acc = 0.f;
  const float* eb = emb + ((size_t)b * SEQ + sg) * 768 + d;
  const float* pp = pos + (size_t)sg * 768 + d;
  for (int s = sg; s < SEQ; s += 4) {
    acc += *eb + *pp;
    eb += 4 * 768; pp += 4 * 768;
  }
  __shared__ float red[4][64];
  red[sg][lane] = acc;
  __syncthreads();
  if (threadIdx.x < 64) {
    float t = red[0][threadIdx.x] + red[1][threadIdx.x] +
              red[2][threadIdx.x] + red[3][threadIdx.x];
    ctxv[b * 768 + chunk * 64 + threadIdx.x] = t * (1.0f / 1024.0f);
  }
}

// ---------------------------------------------------------------- small GEMM  C[Mx768] = A[Mx768] @ W[768x768] (+bias)
__global__ __launch_bounds__(256) void gemm768_kernel(
    const float* __restrict__ A, const float* __restrict__ W,
    const float* __restrict__ bias, float* __restrict__ C, int M) {
  __shared__ __align__(16) float sA[16][68];
  __shared__ __align__(16) float sB[16][68];
  const int bm = blockIdx.x * 64;
  const int bn = blockIdx.y * 64;
  const int tid = threadIdx.x;
  const int tm = (tid >> 4) * 4;
  const int tn = (tid & 15) * 4;
  const int lm = tid >> 2, lkq = (tid & 3) * 4;
  const int lkk = tid >> 4, lnq = (tid & 15) * 4;
  float acc[4][4] = {};
  for (int k0 = 0; k0 < 768; k0 += 16) {
    float4 av = make_float4(0.f, 0.f, 0.f, 0.f);
    if (bm + lm < M) av = *(const float4*)&A[(size_t)(bm + lm) * 768 + k0 + lkq];
    float4 wv = *(const float4*)&W[(size_t)(k0 + lkk) * 768 + bn + lnq];
    __syncthreads();
    sA[lkq + 0][lm] = av.x; sA[lkq + 1][lm] = av.y;
    sA[lkq + 2][lm] = av.z; sA[lkq + 3][lm] = av.w;
    *(float4*)&sB[lkk][lnq] = wv;
    __syncthreads();
#pragma unroll
    for (int kk = 0; kk < 16; ++kk) {
      float4 a = *(const float4*)&sA[kk][tm];
      float4 w = *(const float4*)&sB[kk][tn];
      acc[0][0] += a.x * w.x; acc[0][1] += a.x * w.y; acc[0][2] += a.x * w.z; acc[0][3] += a.x * w.w;
      acc[1][0] += a.y * w.x; acc[1][1] += a.y * w.y; acc[1][2] += a.y * w.z; acc[1][3] += a.y * w.w;
      acc[2][0] += a.z * w.x; acc[2][1] += a.z * w.y; acc[2][2] += a.z * w.z; acc[2][3] += a.z * w.w;
      acc[3][0] += a.w * w.x; acc[3][1] += a.w * w.y; acc[3][2] += a.w * w.z; acc[3][3] += a.w * w.w;
    }
  }
#pragma unroll
  for (int i = 0; i < 4; ++i) {
    int row = bm + tm + i;
    if (row < M) {
#pragma unroll
      for (int j = 0; j < 4; ++j) {
        float o = acc[i][j];
        if (bias) o += bias[bn + tn + j];
        C[(size_t)row * 768 + bn + tn + j] = o;
      }
    }
  }
}

// ---------------------------------------------------------------- 4-way fused projection GEMM (shared A, M=512)
struct ProjParams {
  const float* W[4];
  const float* bias[4];
  float* C[4];
};

__global__ __launch_bounds__(256) void gemm768x4_kernel(
    const float* __restrict__ A, ProjParams pp) {
  __shared__ __align__(16) float sA[16][68];
  __shared__ __align__(16) float sB[16][68];
  const int sel = blockIdx.y / 12;
  const float* W = pp.W[sel];
  const float* bias = pp.bias[sel];
  float* C = pp.C[sel];
  const int bm = blockIdx.x * 64;
  const int bn = (blockIdx.y % 12) * 64;
  const int tid = threadIdx.x;
  const int tm = (tid >> 4) * 4;
  const int tn = (tid & 15) * 4;
  const int lm = tid >> 2, lkq = (tid & 3) * 4;
  const int lkk = tid >> 4, lnq = (tid & 15) * 4;
  float acc[4][4] = {};
  for (int k0 = 0; k0 < 768; k0 += 16) {
    float4 av = *(const float4*)&A[(size_t)(bm + lm) * 768 + k0 + lkq];
    float4 wv = *(const float4*)&W[(size_t)(k0 + lkk) * 768 + bn + lnq];
    __syncthreads();
    sA[lkq + 0][lm] = av.x; sA[lkq + 1][lm] = av.y;
    sA[lkq + 2][lm] = av.z; sA[lkq + 3][lm] = av.w;
    *(float4*)&sB[lkk][lnq] = wv;
    __syncthreads();
#pragma unroll
    for (int kk = 0; kk < 16; ++kk) {
      float4 a = *(const float4*)&sA[kk][tm];
      float4 w = *(const float4*)&sB[kk][tn];
      acc[0][0] += a.x * w.x; acc[0][1] += a.x * w.y; acc[0][2] += a.x * w.z; acc[0][3] += a.x * w.w;
      acc[1][0] += a.y * w.x; acc[1][1] += a.y * w.y; acc[1][2] += a.y * w.z; acc[1][3] += a.y * w.w;
      acc[2][0] += a.z * w.x; acc[2][1] += a.z * w.y; acc[2][2] += a.z * w.z; acc[2][3] += a.z * w.w;
      acc[3][0] += a.w * w.x; acc[3][1] += a.w * w.y; acc[3][2] += a.w * w.z; acc[3][3] += a.w * w.w;
    }
  }
#pragma unroll
  for (int i = 0; i < 4; ++i) {
    int row = bm + tm + i;
#pragma unroll
    for (int j = 0; j < 4; ++j) {
      float o = acc[i][j];
      if (bias) o += bias[bn + tn + j];
      C[(size_t)row * 768 + bn + tn + j] = o;
    }
  }
}

// ---------------------------------------------------------------- fused K+V GEMM via bf16 MFMA
// tile 64x128, 256 threads (4 waves x 16-row strips), K-step 32, grid (64,12)
// out transposed to (B,H,S,64) fp32
__global__ __launch_bounds__(256) void kv_mfma_kernel(
    const ushort* __restrict__ xb,       // (4096,768) bf16
    const ushort* __restrict__ WtK,      // (768 n, 768 k) bf16
    const ushort* __restrict__ WtV,
    const float* __restrict__ bk, const float* __restrict__ bv,
    float* __restrict__ k2, float* __restrict__ v2) {
  __shared__ ushort sA[64][40];          // [m][k] bf16, pad 40 (2-way banks)
  __shared__ ushort sBt[128][40];        // [n][k] bf16
  const int bm = blockIdx.x * 64;
  const bool isV = blockIdx.y >= 6;
  const int bn = (blockIdx.y % 6) * 128;
  const ushort* __restrict__ Wt = isV ? WtV : WtK;
  const float* __restrict__ bias = isV ? bv : bk;
  float* __restrict__ out = isV ? v2 : k2;
  const int t = threadIdx.x;
  const int ar = t >> 2, ac8 = (t & 3) * 8;    // A stage: 64 rows x 32k
  const int wr = t >> 2, wc8 = (t & 3) * 8;    // Wt stage: rows wr, wr+64

  const ushort* __restrict__ Axp = xb + (size_t)(bm + ar) * 768 + ac8;
  const ushort* __restrict__ Wp0 = Wt + (size_t)(bn + wr) * 768 + wc8;
  const ushort* __restrict__ Wp1 = Wt + (size_t)(bn + wr + 64) * 768 + wc8;

  uint4 ra  = *(const uint4*)(Axp);
  uint4 rw0 = *(const uint4*)(Wp0);
  uint4 rw1 = *(const uint4*)(Wp1);

  const int lane = t & 63;
  const int w = t >> 6;                  // wave id -> m strip
  const int lrow = lane & 15;
  const int lk8 = (lane >> 4) * 8;

  f32x4 acc[8] = {};
  for (int k0 = 0; k0 < 768; k0 += 32) {
    __syncthreads();
    *(uint4*)&sA[ar][ac8] = ra;
    *(uint4*)&sBt[wr][wc8] = rw0;
    *(uint4*)&sBt[wr + 64][wc8] = rw1;
    __syncthreads();
    if (k0 + 32 < 768) {                 // register prefetch next slab
      ra  = *(const uint4*)(Axp + k0 + 32);
      rw0 = *(const uint4*)(Wp0 + k0 + 32);
      rw1 = *(const uint4*)(Wp1 + k0 + 32);
    }
    bf16x8 a = *(const bf16x8*)&sA[w * 16 + lrow][lk8];
#pragma unroll
    for (int nf = 0; nf < 8; ++nf) {
      bf16x8 b = *(const bf16x8*)&sBt[nf * 16 + lrow][lk8];
      acc[nf] = __builtin_amdgcn_mfma_f32_16x16x32_bf16(a, b, acc[nf], 0, 0, 0);
    }
  }

  // epilogue: D col=lane&15, row=(lane>>4)*4+r  (m89-verified)
  const int bidx = bm >> 10;
  const int s_base = bm & 1023;
  const int h0 = bn >> 6;
  const int rg = (lane >> 4) * 4;
#pragma unroll
  for (int nf = 0; nf < 8; ++nf) {
    int nl = nf * 16 + lrow;             // 0..127 within strip
    int h = h0 + (nl >> 6);
    int c = nl & 63;
    float bsv = bias[bn + nl];
    float* op = out + (((size_t)(bidx * 12 + h)) * 1024 + s_base + w * 16 + rg) * 64 + c;
#pragma unroll
    for (int r = 0; r < 4; ++r)
      op[(size_t)r * 64] = acc[nf][r] + bsv;
  }
}

// ---------------------------------------------------------------- flash-style attention, 16 queries/block, (B,H,S,64) K/V
__global__ __launch_bounds__(256) void attn2_kernel(
    const float* __restrict__ q, const float* __restrict__ k2,
    const float* __restrict__ v2, float* __restrict__ ctx,
    float* __restrict__ invsum) {
  __shared__ float p[16][1028];
  __shared__ float4 sK[128 * 16];         // swizzled: [s][dq ^ (s&7)]
  __shared__ float4 sQ[16][16];
  __shared__ float linv[16];
  __shared__ float4 part[4][4][4][16];    // [sq][nq][i][dq]

  // XCD-aware remap: one (b,h)'s 8 q-group blocks land on one XCD
  const int xcd = blockIdx.x & 7;
  const int slot = blockIdx.x >> 3;       // 0..47
  const int bh = xcd * 6 + (slot >> 3);   // 0..47
  const int ng = slot & 7;
  const int b = bh / 12, h = bh % 12;
  const int t = threadIdx.x;

  {  // stage Q, fold 1/sqrt(64)
    int nn = t >> 4, dq = t & 15;
    float4 qv = *(const float4*)&q[(size_t)(ng * 16 + nn) * 768 + h * 64 + dq * 4];
    qv.x *= 0.125f; qv.y *= 0.125f; qv.z *= 0.125f; qv.w *= 0.125f;
    sQ[nn][dq] = qv;
  }
  const float4* kbh = (const float4*)(k2 + ((size_t)(b * 12 + h)) * 1024 * 64);
  const float4* vbh = (const float4*)(v2 + ((size_t)(b * 12 + h)) * 1024 * 64);

  const int npair = t >> 5;               // 0..7
  const int g = t & 31;
  const int n0 = npair * 2, n1 = n0 + 1;

  // ---- QK^T into p ----
  for (int c = 0; c < 8; ++c) {
    __syncthreads();
#pragma unroll
    for (int w = 0; w < 8; ++w) {
      int fi = w * 256 + t;
      int sl = fi >> 4, dq = fi & 15;
      sK[sl * 16 + (dq ^ (sl & 7))] = kbh[c * 2048 + fi];
    }
    __syncthreads();
    float4 a0[4] = {}, a1[4] = {};
#pragma unroll
    for (int d0 = 0; d0 < 16; ++d0) {
      float4 q0 = sQ[n0][d0];
      float4 q1 = sQ[n1][d0];
      int slot2 = d0 ^ (g & 7);
#pragma unroll
      for (int u = 0; u < 4; ++u) {
        float4 kv = sK[(g + 32 * u) * 16 + slot2];
        a0[u].x += q0.x * kv.x; a0[u].y += q0.y * kv.y;
        a0[u].z += q0.z * kv.z; a0[u].w += q0.w * kv.w;
        a1[u].x += q1.x * kv.x; a1[u].y += q1.y * kv.y;
        a1[u].z += q1.z * kv.z; a1[u].w += q1.w * kv.w;
      }
    }
#pragma unroll
    for (int u = 0; u < 4; ++u) {
      int s = c * 128 + g + 32 * u;
      p[n0][s] = a0[u].x + a0[u].y + a0[u].z + a0[u].w;
      p[n1][s] = a1[u].x + a1[u].y + a1[u].z + a1[u].w;
    }
  }
  __syncthreads();

  // ---- softmax per row; activity = 1/sum ----
  {
    int n = t >> 4, sub = t & 15;
    float m = -1e30f;
#pragma unroll 8
    for (int u = 0; u < 64; ++u) m = fmaxf(m, p[n][sub + 16 * u]);
    m = fmaxf(m, __shfl_xor(m, 1)); m = fmaxf(m, __shfl_xor(m, 2));
    m = fmaxf(m, __shfl_xor(m, 4)); m = fmaxf(m, __shfl_xor(m, 8));
    float sum = 0.f;
#pragma unroll 8
    for (int u = 0; u < 64; ++u) {
      float e = __expf(p[n][sub + 16 * u] - m);
      p[n][sub + 16 * u] = e;
      sum += e;
    }
    sum += __shfl_xor(sum, 1); sum += __shfl_xor(sum, 2);
    sum += __shfl_xor(sum, 4); sum += __shfl_xor(sum, 8);
    if (sub == 0) {
      float inv = 1.0f / sum;
      linv[n] = inv;
      invsum[(b * 12 + h) * 128 + ng * 16 + n] = inv;
    }
  }

  // ---- PV ----
  const int dq = t & 15, nq = (t >> 4) & 3, sq = t >> 6;
  float4 acc[4] = {};
  for (int c = 0; c < 8; ++c) {
    __syncthreads();
#pragma unroll
    for (int w = 0; w < 8; ++w) {
      int fi = w * 256 + t;
      int sl = fi >> 4, dqq = fi & 15;
      sK[sl * 16 + (dqq ^ (sl & 7))] = vbh[c * 2048 + fi];
    }
    __syncthreads();
#pragma unroll 2
    for (int v4 = 0; v4 < 32; v4 += 4) {
      int sl0 = sq * 32 + v4;
      int s0 = c * 128 + sl0;
      float pr[4][4];
#pragma unroll
      for (int i = 0; i < 4; ++i)
        *(float4*)&pr[i][0] = *(const float4*)&p[nq * 4 + i][s0];
#pragma unroll
      for (int u = 0; u < 4; ++u) {
        int sl = sl0 + u;
        float4 vv = sK[sl * 16 + (dq ^ (sl & 7))];
#pragma unroll
        for (int i = 0; i < 4; ++i) {
          float pw = pr[i][u];
          acc[i].x += pw * vv.x; acc[i].y += pw * vv.y;
          acc[i].z += pw * vv.z; acc[i].w += pw * vv.w;
        }
      }
    }
  }
#pragma unroll
  for (int i = 0; i < 4; ++i) part[sq][nq][i][dq] = acc[i];
  __syncthreads();
  {
    int n = t >> 4, dqq = t & 15;
    float4 r0 = part[0][n >> 2][n & 3][dqq];
    float4 r1 = part[1][n >> 2][n & 3][dqq];
    float4 r2 = part[2][n >> 2][n & 3][dqq];
    float4 r3 = part[3][n >> 2][n & 3][dqq];
    float inv = linv[n];
    float4 o;
    o.x = (r0.x + r1.x + r2.x + r3.x) * inv;
    o.y = (r0.y + r1.y + r2.y + r3.y) * inv;
    o.z = (r0.z + r1.z + r2.z + r3.z) * inv;
    o.w = (r0.w + r1.w + r2.w + r3.w) * inv;
    *(float4*)&ctx[(size_t)(b * 128 + ng * 16 + n) * 768 + h * 64 + dqq * 4] = o;
  }
}

// ---------------------------------------------------------------- entity mask
__global__ void mask_kernel(const float* __restrict__ invsum,
                            float* __restrict__ mask_out) {
  int t = threadIdx.x;                   // 512 = B*N
  int b = t >> 7, n = t & 127;
  float a = 0.f;
  for (int h = 0; h < 12; ++h) a = fmaxf(a, invsum[(b * 12 + h) * 128 + n]);
  mask_out[t] = (a > 0.001f) ? 1.0f : 0.0f;
}

// ---------------------------------------------------------------- masked entities out
__global__ __launch_bounds__(256) void entmask_kernel(
    const float* __restrict__ ent, const float* __restrict__ mask,
    float* __restrict__ out) {
  int bi = blockIdx.x;                   // b*128+i
  float m = mask[bi];
  for (int e = threadIdx.x; e < 768; e += 256)
    out[(size_t)bi * 768 + e] = ent[(size_t)bi * 768 + e] * m;
}

// ---------------------------------------------------------------- fused edge refinement + gate + mask
__global__ __launch_bounds__(256) void refine_kernel(
    const float* __restrict__ A1, const float* __restrict__ B1,
    const float* __restrict__ C1, const float* __restrict__ w1g,
    const float* __restrict__ W2, const float* __restrict__ b2,
    const float* __restrict__ Ag, const float* __restrict__ Bg,
    const float* __restrict__ Wg2, const float* __restrict__ bg2,
    const float* __restrict__ graph_init, const float* __restrict__ mask,
    float* __restrict__ graph_out) {
  const int bi = blockIdx.x >> 2;        // b*128 + i
  const int jq = blockIdx.x & 3;         // j-quarter
  const int b = bi >> 7;
  const int lane = threadIdx.x & 63, wv = threadIdx.x >> 6;

  float base[12], w1gr[12], w2r[12], agr[12], wg2r[12];
#pragma unroll
  for (int r = 0; r < 12; ++r) {
    int e = r * 64 + lane;
    base[r] = A1[(size_t)bi * 768 + e] + C1[b * 768 + e];
    w1gr[r] = w1g[e];
    w2r[r]  = W2[e];
    agr[r]  = Ag[(size_t)bi * 768 + e];
    wg2r[r] = Wg2[e];
  }
  const float b2s = b2[0], bg2s = bg2[0];
  const float mi = mask[bi];

  const int jend = jq * 32 + 32;
  for (int j = jq * 32 + wv; j < jend; j += 4) {
    float g = graph_init[(size_t)bi * 128 + j] * 1.6f - 0.8f;
    const float* B1j = &B1[((size_t)(b * NE + j)) * 768 + lane];
    const float* Bgj = &Bg[((size_t)(b * NE + j)) * 768 + lane];
    float pre[12], gpre[12];
#pragma unroll
    for (int r = 0; r < 12; ++r) {
      pre[r]  = base[r] + B1j[r * 64];
      gpre[r] = agr[r] + Bgj[r * 64];
    }
#pragma unroll
    for (int st = 0; st < 3; ++st) {
      float acc = 0.f;
#pragma unroll
      for (int r = 0; r < 12; ++r) {
        float hx = pre[r] + g * w1gr[r];
        acc += gelu_fast(hx) * w2r[r];
      }
      acc += __shfl_xor(acc, 1);  acc += __shfl_xor(acc, 2);
      acc += __shfl_xor(acc, 4);  acc += __shfl_xor(acc, 8);
      acc += __shfl_xor(acc, 16); acc += __shfl_xor(acc, 32);
      g += tanh_fast(acc + b2s);
    }
    float gacc = 0.f;
#pragma unroll
    for (int r = 0; r < 12; ++r) gacc += gelu_fast(gpre[r]) * wg2r[r];
    gacc += __shfl_xor(gacc, 1);  gacc += __shfl_xor(gacc, 2);
    gacc += __shfl_xor(gacc, 4);  gacc += __shfl_xor(gacc, 8);
    gacc += __shfl_xor(gacc, 16); gacc += __shfl_xor(gacc, 32);
    float gate = sigmoid_fast(gacc + bg2s);
    if (lane == 0)
      graph_out[(size_t)bi * 128 + j] = g * gate * mi * mask[b * NE + j];
  }
}

}  // namespace

extern "C" void kernel_launch(void* const* d_in, const int* in_sizes, int n_in,
                              void* d_out, int out_size, void* d_ws, size_t ws_size,
                              hipStream_t stream) {
  const float* emb  = (const float*)d_in[0];
  const float* ginit= (const float*)d_in[1];
  const float* lib  = (const float*)d_in[2];
  const float* pos  = (const float*)d_in[3];
  const float* Wq   = (const float*)d_in[4];
  const float* bq   = (const float*)d_in[5];
  const float* Wk   = (const float*)d_in[6];
  const float* bk   = (const float*)d_in[7];
  const float* Wv   = (const float*)d_in[8];
  const float* bv   = (const float*)d_in[9];
  const float* Wo   = (const float*)d_in[10];
  const float* bo   = (const float*)d_in[11];
  const float* W1   = (const float*)d_in[12];
  const float* b1   = (const float*)d_in[13];
  const float* W2   = (const float*)d_in[14];
  const float* b2   = (const float*)d_in[15];
  const float* Wg1  = (const float*)d_in[16];
  const float* bg1  = (const float*)d_in[17];
  const float* Wg2  = (const float*)d_in[18];
  const float* bg2  = (const float*)d_in[19];

  float* ws = (float*)d_ws;
  float* k2   = ws + 0;                 // (B,H,S,64)  3,145,728
  float* v2   = ws + 3145728;           // (B,H,S,64)  3,145,728
  // bf16 x occupies [6291456, 7864320) float-words; dead after kv_mfma
  ushort* xb  = (ushort*)(ws + 6291456);     // 3,145,728 bf16
  float* A1   = ws + 6291456;           // reuse after kv
  float* B1   = ws + 6684672;
  float* Ag   = ws + 7077888;
  float* Bg   = ws + 7471104;           // ends 7864320
  ushort* WtK = (ushort*)(ws + 7864320);     // 589,824 bf16 (294,912 fw)
  ushort* WtV = WtK + 589824;                // ends 8454144 fw
  float* q_   = ws + 9437184;           // 98,304
  float* ctx_ = ws + 9535488;           // 393,216
  float* ent_ = ws + 9928704;           // 393,216
  float* ctxv = ws + 10321920;          // 3,072
  float* C1   = ws + 10324992;          // 3,072
  float* invs = ws + 10328064;          // 6,144

  float* out_ent   = (float*)d_out;           // 393,216
  float* out_graph = out_ent + 393216;        // 65,536
  float* out_mask  = out_ent + 458752;        // 512

  // 0. Wk/Wv -> transposed bf16
  wconv_kernel<<<dim3(12, 12, 2), 256, 0, stream>>>(Wk, Wv, WtK, WtV);
  // 1. x = emb + pos (bf16)
  posadd_bf16_kernel<<<1536, 256, 0, stream>>>(emb, pos, xb);
  // 2. context = mean_s (emb+pos)
  ctxmean_kernel<<<48, 256, 0, stream>>>(emb, pos, ctxv);
  // 3. q = lib @ Wq + bq
  gemm768_kernel<<<dim3(2, 12), 256, 0, stream>>>(lib, Wq, bq, q_, 128);
  // 4. k2/v2 = x @ Wk/Wv + b via bf16 MFMA, transposed to (B,H,S,64)
  kv_mfma_kernel<<<dim3(64, 12), 256, 0, stream>>>(xb, WtK, WtV, bk, bv, k2, v2);
  // 5. attention -> ctx (B,N,H*K), invsum (B,H,N)
  attn2_kernel<<<384, 256, 0, stream>>>(q_, k2, v2, ctx_, invs);
  // 6. entity mask
  mask_kernel<<<1, 512, 0, stream>>>(invs, out_mask);
  // 7. entities = ctx @ Wo + bo
  gemm768_kernel<<<dim3(8, 12), 256, 0, stream>>>(ctx_, Wo, bo, ent_, 512);
  // 8. masked entities out
  entmask_kernel<<<512, 256, 0, stream>>>(ent_, out_mask, out_ent);
  // 9. fused per-entity projections for edge MLPs (A1,B1,Ag,Bg)
  ProjParams pp;
  pp.W[0] = W1;              pp.bias[0] = nullptr; pp.C[0] = A1;
  pp.W[1] = W1 + 589824;     pp.bias[1] = nullptr; pp.C[1] = B1;
  pp.W[2] = Wg1;             pp.bias[2] = bg1;     pp.C[2] = Ag;
  pp.W[3] = Wg1 + 589824;    pp.bias[3] = nullptr; pp.C[3] = Bg;
  gemm768x4_kernel<<<dim3(8, 48), 256, 0, stream>>>(ent_, pp);
  // 10. C1 = context @ W1d + b1
  gemm768_kernel<<<dim3(1, 12), 256, 0, stream>>>(ctxv, W1 + 1537 * 768, b1, C1, 4);
  // 11. fused edge refinement (3 steps) + gate + entity masking
  refine_kernel<<<2048, 256, 0, stream>>>(A1, B1, C1, W1 + 1536 * 768, W2, b2,
                                          Ag, Bg, Wg2, bg2, ginit, out_mask,
                                          out_graph);
}

// Round 8
// 615.368 us; speedup vs baseline: 1.5966x; 1.0044x over previous
//
#include <hip/hip_runtime.h>
#include <hip/hip_bf16.h>
#include <math.h>

namespace {
constexpr int SEQ  = 1024;
constexpr int NE   = 128;

typedef float f32x4  __attribute__((ext_vector_type(4)));
typedef short bf16x8 __attribute__((ext_vector_type(8)));

__device__ __forceinline__ float rcp_fast(float x) {
  return __builtin_amdgcn_rcpf(x);
}

__device__ __forceinline__ float gelu_fast(float x) {
  float x2 = x * x;
  float t = fmaf(x2, -0.1029443f, -2.3022093f);
  return x * rcp_fast(1.0f + exp2f(x * t));
}

__device__ __forceinline__ float tanh_fast(float x) {
  return 1.0f - 2.0f * rcp_fast(1.0f + exp2f(x * 2.8853901f));
}

__device__ __forceinline__ float sigmoid_fast(float x) {
  return rcp_fast(1.0f + exp2f(x * -1.4426950f));
}

__device__ __forceinline__ ushort f2bf(float f) {
  union { float f; unsigned u; } c; c.f = f;
  unsigned u = c.u;
  u += 0x7FFF + ((u >> 16) & 1);            // RNE
  return (ushort)(u >> 16);
}

// ---------------------------------------------------------------- pos add -> bf16 x
__global__ __launch_bounds__(256) void posadd_bf16_kernel(
    const float* __restrict__ emb, const float* __restrict__ pos,
    ushort* __restrict__ xb) {
  int i = blockIdx.x * 256 + threadIdx.x;      // 8-float chunk; total 393216
  const int perB = SEQ * 768 / 8;              // 98304
  int pi = i - (i / perB) * perB;
  float4 e0 = ((const float4*)emb)[i * 2];
  float4 e1 = ((const float4*)emb)[i * 2 + 1];
  float4 p0 = ((const float4*)pos)[pi * 2];
  float4 p1 = ((const float4*)pos)[pi * 2 + 1];
  ushort o[8];
  o[0] = f2bf(e0.x + p0.x); o[1] = f2bf(e0.y + p0.y);
  o[2] = f2bf(e0.z + p0.z); o[3] = f2bf(e0.w + p0.w);
  o[4] = f2bf(e1.x + p1.x); o[5] = f2bf(e1.y + p1.y);
  o[6] = f2bf(e1.z + p1.z); o[7] = f2bf(e1.w + p1.w);
  *(uint4*)&xb[(size_t)i * 8] = *(uint4*)o;
}

// ---------------------------------------------------------------- weight transpose-convert: W[k][n] f32 -> Wt[n][k] bf16
__global__ __launch_bounds__(256) void wconv_kernel(
    const float* __restrict__ Wk, const float* __restrict__ Wv,
    ushort* __restrict__ WtK, ushort* __restrict__ WtV) {
  const float* __restrict__ W  = blockIdx.z ? Wv : Wk;
  ushort* __restrict__ Wt = blockIdx.z ? WtV : WtK;
  const int k0 = blockIdx.x * 64, n0 = blockIdx.y * 64;
  __shared__ ushort sT[64][72];               // [n][k], padded
  const int t = threadIdx.x;
  const int rr = t >> 4, c4 = (t & 15) * 4;
#pragma unroll
  for (int i = 0; i < 4; ++i) {
    int r = rr + 16 * i;
    float4 v = *(const float4*)&W[(size_t)(k0 + r) * 768 + n0 + c4];
    sT[c4 + 0][r] = f2bf(v.x);
    sT[c4 + 1][r] = f2bf(v.y);
    sT[c4 + 2][r] = f2bf(v.z);
    sT[c4 + 3][r] = f2bf(v.w);
  }
  __syncthreads();
#pragma unroll
  for (int j = 0; j < 2; ++j) {
    int cid = t + 256 * j;
    int nr = cid >> 3, kc8 = (cid & 7) * 8;
    *(uint4*)&Wt[(size_t)(n0 + nr) * 768 + k0 + kc8] = *(uint4*)&sT[nr][kc8];
  }
}

// ---------------------------------------------------------------- context mean (from emb+pos directly)
__global__ __launch_bounds__(256) void ctxmean_kernel(
    const float* __restrict__ emb, const float* __restrict__ pos,
    float* __restrict__ ctxv) {
  int b = blockIdx.x / 12, chunk = blockIdx.x % 12;
  int lane = threadIdx.x & 63, sg = threadIdx.x >> 6;
  int d = chunk * 64 + lane;
  float acc = 0.f;
  const float* eb = emb + ((size_t)b * SEQ + sg) * 768 + d;
  const float* pp = pos + (size_t)sg * 768 + d;
  for (int s = sg; s < SEQ; s += 4) {
    acc += *eb + *pp;
    eb += 4 * 768; pp += 4 * 768;
  }
  __shared__ float red[4][64];
  red[sg][lane] = acc;
  __syncthreads();
  if (threadIdx.x < 64) {
    float t = red[0][threadIdx.x] + red[1][threadIdx.x] +
              red[2][threadIdx.x] + red[3][threadIdx.x];
    ctxv[b * 768 + chunk * 64 + threadIdx.x] = t * (1.0f / 1024.0f);
  }
}

// ---------------------------------------------------------------- small GEMM  C[Mx768] = A[Mx768] @ W[768x768] (+bias)
__global__ __launch_bounds__(256) void gemm768_kernel(
    const float* __restrict__ A, const float* __restrict__ W,
    const float* __restrict__ bias, float* __restrict__ C, int M) {
  __shared__ __align__(16) float sA[16][68];
  __shared__ __align__(16) float sB[16][68];
  const int bm = blockIdx.x * 64;
  const int bn = blockIdx.y * 64;
  const int tid = threadIdx.x;
  const int tm = (tid >> 4) * 4;
  const int tn = (tid & 15) * 4;
  const int lm = tid >> 2, lkq = (tid & 3) * 4;
  const int lkk = tid >> 4, lnq = (tid & 15) * 4;
  float acc[4][4] = {};
  for (int k0 = 0; k0 < 768; k0 += 16) {
    float4 av = make_float4(0.f, 0.f, 0.f, 0.f);
    if (bm + lm < M) av = *(const float4*)&A[(size_t)(bm + lm) * 768 + k0 + lkq];
    float4 wv = *(const float4*)&W[(size_t)(k0 + lkk) * 768 + bn + lnq];
    __syncthreads();
    sA[lkq + 0][lm] = av.x; sA[lkq + 1][lm] = av.y;
    sA[lkq + 2][lm] = av.z; sA[lkq + 3][lm] = av.w;
    *(float4*)&sB[lkk][lnq] = wv;
    __syncthreads();
#pragma unroll
    for (int kk = 0; kk < 16; ++kk) {
      float4 a = *(const float4*)&sA[kk][tm];
      float4 w = *(const float4*)&sB[kk][tn];
      acc[0][0] += a.x * w.x; acc[0][1] += a.x * w.y; acc[0][2] += a.x * w.z; acc[0][3] += a.x * w.w;
      acc[1][0] += a.y * w.x; acc[1][1] += a.y * w.y; acc[1][2] += a.y * w.z; acc[1][3] += a.y * w.w;
      acc[2][0] += a.z * w.x; acc[2][1] += a.z * w.y; acc[2][2] += a.z * w.z; acc[2][3] += a.z * w.w;
      acc[3][0] += a.w * w.x; acc[3][1] += a.w * w.y; acc[3][2] += a.w * w.z; acc[3][3] += a.w * w.w;
    }
  }
#pragma unroll
  for (int i = 0; i < 4; ++i) {
    int row = bm + tm + i;
    if (row < M) {
#pragma unroll
      for (int j = 0; j < 4; ++j) {
        float o = acc[i][j];
        if (bias) o += bias[bn + tn + j];
        C[(size_t)row * 768 + bn + tn + j] = o;
      }
    }
  }
}

// ---------------------------------------------------------------- 4-way fused projection GEMM (shared A, M=512)
struct ProjParams {
  const float* W[4];
  const float* bias[4];
  float* C[4];
};

__global__ __launch_bounds__(256) void gemm768x4_kernel(
    const float* __restrict__ A, ProjParams pp) {
  __shared__ __align__(16) float sA[16][68];
  __shared__ __align__(16) float sB[16][68];
  const int sel = blockIdx.y / 12;
  const float* W = pp.W[sel];
  const float* bias = pp.bias[sel];
  float* C = pp.C[sel];
  const int bm = blockIdx.x * 64;
  const int bn = (blockIdx.y % 12) * 64;
  const int tid = threadIdx.x;
  const int tm = (tid >> 4) * 4;
  const int tn = (tid & 15) * 4;
  const int lm = tid >> 2, lkq = (tid & 3) * 4;
  const int lkk = tid >> 4, lnq = (tid & 15) * 4;
  float acc[4][4] = {};
  for (int k0 = 0; k0 < 768; k0 += 16) {
    float4 av = *(const float4*)&A[(size_t)(bm + lm) * 768 + k0 + lkq];
    float4 wv = *(const float4*)&W[(size_t)(k0 + lkk) * 768 + bn + lnq];
    __syncthreads();
    sA[lkq + 0][lm] = av.x; sA[lkq + 1][lm] = av.y;
    sA[lkq + 2][lm] = av.z; sA[lkq + 3][lm] = av.w;
    *(float4*)&sB[lkk][lnq] = wv;
    __syncthreads();
#pragma unroll
    for (int kk = 0; kk < 16; ++kk) {
      float4 a = *(const float4*)&sA[kk][tm];
      float4 w = *(const float4*)&sB[kk][tn];
      acc[0][0] += a.x * w.x; acc[0][1] += a.x * w.y; acc[0][2] += a.x * w.z; acc[0][3] += a.x * w.w;
      acc[1][0] += a.y * w.x; acc[1][1] += a.y * w.y; acc[1][2] += a.y * w.z; acc[1][3] += a.y * w.w;
      acc[2][0] += a.z * w.x; acc[2][1] += a.z * w.y; acc[2][2] += a.z * w.z; acc[2][3] += a.z * w.w;
      acc[3][0] += a.w * w.x; acc[3][1] += a.w * w.y; acc[3][2] += a.w * w.z; acc[3][3] += a.w * w.w;
    }
  }
#pragma unroll
  for (int i = 0; i < 4; ++i) {
    int row = bm + tm + i;
#pragma unroll
    for (int j = 0; j < 4; ++j) {
      float o = acc[i][j];
      if (bias) o += bias[bn + tn + j];
      C[(size_t)row * 768 + bn + tn + j] = o;
    }
  }
}

// ---------------------------------------------------------------- fused K+V GEMM via bf16 MFMA
__global__ __launch_bounds__(256) void kv_mfma_kernel(
    const ushort* __restrict__ xb,       // (4096,768) bf16
    const ushort* __restrict__ WtK,      // (768 n, 768 k) bf16
    const ushort* __restrict__ WtV,
    const float* __restrict__ bk, const float* __restrict__ bv,
    float* __restrict__ k2, float* __restrict__ v2) {
  __shared__ ushort sA[64][40];          // [m][k] bf16, pad 40
  __shared__ ushort sBt[128][40];        // [n][k] bf16
  const int bm = blockIdx.x * 64;
  const bool isV = blockIdx.y >= 6;
  const int bn = (blockIdx.y % 6) * 128;
  const ushort* __restrict__ Wt = isV ? WtV : WtK;
  const float* __restrict__ bias = isV ? bv : bk;
  float* __restrict__ out = isV ? v2 : k2;
  const int t = threadIdx.x;
  const int ar = t >> 2, ac8 = (t & 3) * 8;
  const int wr = t >> 2, wc8 = (t & 3) * 8;

  const ushort* __restrict__ Axp = xb + (size_t)(bm + ar) * 768 + ac8;
  const ushort* __restrict__ Wp0 = Wt + (size_t)(bn + wr) * 768 + wc8;
  const ushort* __restrict__ Wp1 = Wt + (size_t)(bn + wr + 64) * 768 + wc8;

  uint4 ra  = *(const uint4*)(Axp);
  uint4 rw0 = *(const uint4*)(Wp0);
  uint4 rw1 = *(const uint4*)(Wp1);

  const int lane = t & 63;
  const int w = t >> 6;
  const int lrow = lane & 15;
  const int lk8 = (lane >> 4) * 8;

  f32x4 acc[8] = {};
  for (int k0 = 0; k0 < 768; k0 += 32) {
    __syncthreads();
    *(uint4*)&sA[ar][ac8] = ra;
    *(uint4*)&sBt[wr][wc8] = rw0;
    *(uint4*)&sBt[wr + 64][wc8] = rw1;
    __syncthreads();
    if (k0 + 32 < 768) {
      ra  = *(const uint4*)(Axp + k0 + 32);
      rw0 = *(const uint4*)(Wp0 + k0 + 32);
      rw1 = *(const uint4*)(Wp1 + k0 + 32);
    }
    bf16x8 a = *(const bf16x8*)&sA[w * 16 + lrow][lk8];
#pragma unroll
    for (int nf = 0; nf < 8; ++nf) {
      bf16x8 b = *(const bf16x8*)&sBt[nf * 16 + lrow][lk8];
      acc[nf] = __builtin_amdgcn_mfma_f32_16x16x32_bf16(a, b, acc[nf], 0, 0, 0);
    }
  }

  const int bidx = bm >> 10;
  const int s_base = bm & 1023;
  const int h0 = bn >> 6;
  const int rg = (lane >> 4) * 4;
#pragma unroll
  for (int nf = 0; nf < 8; ++nf) {
    int nl = nf * 16 + lrow;
    int h = h0 + (nl >> 6);
    int c = nl & 63;
    float bsv = bias[bn + nl];
    float* op = out + (((size_t)(bidx * 12 + h)) * 1024 + s_base + w * 16 + rg) * 64 + c;
#pragma unroll
    for (int r = 0; r < 4; ++r)
      op[(size_t)r * 64] = acc[nf][r] + bsv;
  }
}

// ---------------------------------------------------------------- flash attention (online softmax), 16 queries/block
// LDS ~45KB -> 3 blocks/CU; swizzle ^(s&15); T14 reg-staged K/V
__global__ __launch_bounds__(256) void attn2_kernel(
    const float* __restrict__ q, const float* __restrict__ k2,
    const float* __restrict__ v2, float* __restrict__ ctx,
    float* __restrict__ invsum) {
  __shared__ float4 sK[2048];             // 32KB; aliased as part[] at end
  __shared__ float p[16][144];            // chunk scores, stride 144 (conflict-free)
  __shared__ float4 sQ[16][16];
  __shared__ float frow[16];
  __shared__ float linv[16];

  // XCD-aware remap: one (b,h)'s 8 q-group blocks land on one XCD
  const int xcd = blockIdx.x & 7;
  const int slot = blockIdx.x >> 3;       // 0..47
  const int bh = xcd * 6 + (slot >> 3);   // 0..47
  const int ng = slot & 7;
  const int b = bh / 12, h = bh % 12;
  const int t = threadIdx.x;

  {  // stage Q, fold 1/sqrt(64)
    int nn = t >> 4, dq = t & 15;
    float4 qv = *(const float4*)&q[(size_t)(ng * 16 + nn) * 768 + h * 64 + dq * 4];
    qv.x *= 0.125f; qv.y *= 0.125f; qv.z *= 0.125f; qv.w *= 0.125f;
    sQ[nn][dq] = qv;
  }
  const float4* kbh = (const float4*)(k2 + ((size_t)(b * 12 + h)) * 1024 * 64);
  const float4* vbh = (const float4*)(v2 + ((size_t)(b * 12 + h)) * 1024 * 64);

  // role indices
  const int g = t & 31, npair = t >> 5;           // QK: rows n0,n1; 4 s each
  const int n0 = npair * 2, n1 = n0 + 1;
  const int rn = t >> 4, sub = t & 15;            // softmax rows
  const int dq = t & 15, nq = (t >> 4) & 3, sq = t >> 6;  // PV

  float m_run = -1e30f, sum_run = 0.f;
  float4 acc[4] = {};
  float4 kreg[8], vreg[8];

#pragma unroll
  for (int w = 0; w < 8; ++w) kreg[w] = kbh[w * 256 + t];

  for (int c = 0; c < 8; ++c) {
    __syncthreads();                       // sK free (prev PV done)
#pragma unroll
    for (int w = 0; w < 8; ++w) {          // K chunk -> LDS (swizzled)
      int fi = w * 256 + t;
      int sl = fi >> 4, dd = fi & 15;
      sK[sl * 16 + (dd ^ (sl & 15))] = kreg[w];
    }
    __syncthreads();
#pragma unroll
    for (int w = 0; w < 8; ++w)            // issue V loads (in flight over scores)
      vreg[w] = vbh[c * 2048 + w * 256 + t];

    // ---- scores for this chunk ----
    float4 a0[4] = {}, a1[4] = {};
#pragma unroll
    for (int d0 = 0; d0 < 16; ++d0) {
      float4 q0 = sQ[n0][d0];
      float4 q1 = sQ[n1][d0];
      int slot2 = d0 ^ (g & 15);
#pragma unroll
      for (int u = 0; u < 4; ++u) {
        float4 kv = sK[(g + 32 * u) * 16 + slot2];
        a0[u].x += q0.x * kv.x; a0[u].y += q0.y * kv.y;
        a0[u].z += q0.z * kv.z; a0[u].w += q0.w * kv.w;
        a1[u].x += q1.x * kv.x; a1[u].y += q1.y * kv.y;
        a1[u].z += q1.z * kv.z; a1[u].w += q1.w * kv.w;
      }
    }
#pragma unroll
    for (int u = 0; u < 4; ++u) {
      int s = g + 32 * u;
      p[n0][s] = a0[u].x + a0[u].y + a0[u].z + a0[u].w;
      p[n1][s] = a1[u].x + a1[u].y + a1[u].z + a1[u].w;
    }
    __syncthreads();                       // p done; sK reads done

    // ---- online softmax update ----
    float cm = -1e30f;
#pragma unroll
    for (int u = 0; u < 8; ++u) cm = fmaxf(cm, p[rn][sub + 16 * u]);
    cm = fmaxf(cm, __shfl_xor(cm, 1)); cm = fmaxf(cm, __shfl_xor(cm, 2));
    cm = fmaxf(cm, __shfl_xor(cm, 4)); cm = fmaxf(cm, __shfl_xor(cm, 8));
    float mn = fmaxf(m_run, cm);
    float f = __expf(m_run - mn);
    float csum = 0.f;
#pragma unroll
    for (int u = 0; u < 8; ++u) {
      float e = __expf(p[rn][sub + 16 * u] - mn);
      p[rn][sub + 16 * u] = e;
      csum += e;
    }
    csum += __shfl_xor(csum, 1); csum += __shfl_xor(csum, 2);
    csum += __shfl_xor(csum, 4); csum += __shfl_xor(csum, 8);
    sum_run = sum_run * f + csum;
    m_run = mn;
    if (sub == 0) frow[rn] = f;

#pragma unroll
    for (int w = 0; w < 8; ++w) {          // V chunk -> LDS (same buffer)
      int fi = w * 256 + t;
      int sl = fi >> 4, dd = fi & 15;
      sK[sl * 16 + (dd ^ (sl & 15))] = vreg[w];
    }
    __syncthreads();                       // V + frow + exp(p) ready

    if (c < 7) {
#pragma unroll
      for (int w = 0; w < 8; ++w)          // issue next-K loads over PV
        kreg[w] = kbh[(c + 1) * 2048 + w * 256 + t];
    }

    // ---- PV accumulate with rescale ----
#pragma unroll
    for (int i = 0; i < 4; ++i) {
      float fr = frow[nq * 4 + i];
      acc[i].x *= fr; acc[i].y *= fr; acc[i].z *= fr; acc[i].w *= fr;
    }
#pragma unroll 2
    for (int v4 = 0; v4 < 32; v4 += 4) {
      int sl0 = sq * 32 + v4;
      float pr[4][4];
#pragma unroll
      for (int i = 0; i < 4; ++i)
        *(float4*)&pr[i][0] = *(const float4*)&p[nq * 4 + i][sl0];
#pragma unroll
      for (int u = 0; u < 4; ++u) {
        int sl = sl0 + u;
        float4 vv = sK[sl * 16 + (dq ^ (sl & 15))];
#pragma unroll
        for (int i = 0; i < 4; ++i) {
          float pw = pr[i][u];
          acc[i].x += pw * vv.x; acc[i].y += pw * vv.y;
          acc[i].z += pw * vv.z; acc[i].w += pw * vv.w;
        }
      }
    }
  }

  // activity = 1/sum
  if (sub == 0) {
    float inv = 1.0f / sum_run;
    linv[rn] = inv;
    invsum[(b * 12 + h) * 128 + ng * 16 + rn] = inv;
  }
  __syncthreads();                         // last PV reads of sK done
  // partial-sum reduction, part[] aliased into sK
#pragma unroll
  for (int i = 0; i < 4; ++i)
    sK[((sq * 4 + nq) * 4 + i) * 16 + dq] = acc[i];
  __syncthreads();
  {
    int n = t >> 4, dqq = t & 15;
    float4 r0 = sK[((0 * 4 + (n >> 2)) * 4 + (n & 3)) * 16 + dqq];
    float4 r1 = sK[((1 * 4 + (n >> 2)) * 4 + (n & 3)) * 16 + dqq];
    float4 r2 = sK[((2 * 4 + (n >> 2)) * 4 + (n & 3)) * 16 + dqq];
    float4 r3 = sK[((3 * 4 + (n >> 2)) * 4 + (n & 3)) * 16 + dqq];
    float inv = linv[n];
    float4 o;
    o.x = (r0.x + r1.x + r2.x + r3.x) * inv;
    o.y = (r0.y + r1.y + r2.y + r3.y) * inv;
    o.z = (r0.z + r1.z + r2.z + r3.z) * inv;
    o.w = (r0.w + r1.w + r2.w + r3.w) * inv;
    *(float4*)&ctx[(size_t)(b * 128 + ng * 16 + n) * 768 + h * 64 + dqq * 4] = o;
  }
}

// ---------------------------------------------------------------- entity mask
__global__ void mask_kernel(const float* __restrict__ invsum,
                            float* __restrict__ mask_out) {
  int t = threadIdx.x;                   // 512 = B*N
  int b = t >> 7, n = t & 127;
  float a = 0.f;
  for (int h = 0; h < 12; ++h) a = fmaxf(a, invsum[(b * 12 + h) * 128 + n]);
  mask_out[t] = (a > 0.001f) ? 1.0f : 0.0f;
}

// ---------------------------------------------------------------- masked entities out
__global__ __launch_bounds__(256) void entmask_kernel(
    const float* __restrict__ ent, const float* __restrict__ mask,
    float* __restrict__ out) {
  int bi = blockIdx.x;                   // b*128+i
  float m = mask[bi];
  for (int e = threadIdx.x; e < 768; e += 256)
    out[(size_t)bi * 768 + e] = ent[(size_t)bi * 768 + e] * m;
}

// ---------------------------------------------------------------- fused edge refinement + gate + mask
__global__ __launch_bounds__(256) void refine_kernel(
    const float* __restrict__ A1, const float* __restrict__ B1,
    const float* __restrict__ C1, const float* __restrict__ w1g,
    const float* __restrict__ W2, const float* __restrict__ b2,
    const float* __restrict__ Ag, const float* __restrict__ Bg,
    const float* __restrict__ Wg2, const float* __restrict__ bg2,
    const float* __restrict__ graph_init, const float* __restrict__ mask,
    float* __restrict__ graph_out) {
  const int bi = blockIdx.x >> 2;        // b*128 + i
  const int jq = blockIdx.x & 3;         // j-quarter
  const int b = bi >> 7;
  const int lane = threadIdx.x & 63, wv = threadIdx.x >> 6;

  float base[12], w1gr[12], w2r[12], agr[12], wg2r[12];
#pragma unroll
  for (int r = 0; r < 12; ++r) {
    int e = r * 64 + lane;
    base[r] = A1[(size_t)bi * 768 + e] + C1[b * 768 + e];
    w1gr[r] = w1g[e];
    w2r[r]  = W2[e];
    agr[r]  = Ag[(size_t)bi * 768 + e];
    wg2r[r] = Wg2[e];
  }
  const float b2s = b2[0], bg2s = bg2[0];
  const float mi = mask[bi];

  const int jend = jq * 32 + 32;
  for (int j = jq * 32 + wv; j < jend; j += 4) {
    float g = graph_init[(size_t)bi * 128 + j] * 1.6f - 0.8f;
    const float* B1j = &B1[((size_t)(b * NE + j)) * 768 + lane];
    const float* Bgj = &Bg[((size_t)(b * NE + j)) * 768 + lane];
    float pre[12], gpre[12];
#pragma unroll
    for (int r = 0; r < 12; ++r) {
      pre[r]  = base[r] + B1j[r * 64];
      gpre[r] = agr[r] + Bgj[r * 64];
    }
#pragma unroll
    for (int st = 0; st < 3; ++st) {
      float acc = 0.f;
#pragma unroll
      for (int r = 0; r < 12; ++r) {
        float hx = pre[r] + g * w1gr[r];
        acc += gelu_fast(hx) * w2r[r];
      }
      acc += __shfl_xor(acc, 1);  acc += __shfl_xor(acc, 2);
      acc += __shfl_xor(acc, 4);  acc += __shfl_xor(acc, 8);
      acc += __shfl_xor(acc, 16); acc += __shfl_xor(acc, 32);
      g += tanh_fast(acc + b2s);
    }
    float gacc = 0.f;
#pragma unroll
    for (int r = 0; r < 12; ++r) gacc += gelu_fast(gpre[r]) * wg2r[r];
    gacc += __shfl_xor(gacc, 1);  gacc += __shfl_xor(gacc, 2);
    gacc += __shfl_xor(gacc, 4);  gacc += __shfl_xor(gacc, 8);
    gacc += __shfl_xor(gacc, 16); gacc += __shfl_xor(gacc, 32);
    float gate = sigmoid_fast(gacc + bg2s);
    if (lane == 0)
      graph_out[(size_t)bi * 128 + j] = g * gate * mi * mask[b * NE + j];
  }
}

}  // namespace

extern "C" void kernel_launch(void* const* d_in, const int* in_sizes, int n_in,
                              void* d_out, int out_size, void* d_ws, size_t ws_size,
                              hipStream_t stream) {
  const float* emb  = (const float*)d_in[0];
  const float* ginit= (const float*)d_in[1];
  const float* lib  = (const float*)d_in[2];
  const float* pos  = (const float*)d_in[3];
  const float* Wq   = (const float*)d_in[4];
  const float* bq   = (const float*)d_in[5];
  const float* Wk   = (const float*)d_in[6];
  const float* bk   = (const float*)d_in[7];
  const float* Wv   = (const float*)d_in[8];
  const float* bv   = (const float*)d_in[9];
  const float* Wo   = (const float*)d_in[10];
  const float* bo   = (const float*)d_in[11];
  const float* W1   = (const float*)d_in[12];
  const float* b1   = (const float*)d_in[13];
  const float* W2   = (const float*)d_in[14];
  const float* b2   = (const float*)d_in[15];
  const float* Wg1  = (const float*)d_in[16];
  const float* bg1  = (const float*)d_in[17];
  const float* Wg2  = (const float*)d_in[18];
  const float* bg2  = (const float*)d_in[19];

  float* ws = (float*)d_ws;
  float* k2   = ws + 0;                 // (B,H,S,64)  3,145,728
  float* v2   = ws + 3145728;           // (B,H,S,64)  3,145,728
  ushort* xb  = (ushort*)(ws + 6291456);     // bf16 x; dead after kv_mfma
  float* A1   = ws + 6291456;           // reuse after kv
  float* B1   = ws + 6684672;
  float* Ag   = ws + 7077888;
  float* Bg   = ws + 7471104;           // ends 7864320
  ushort* WtK = (ushort*)(ws + 7864320);
  ushort* WtV = WtK + 589824;
  float* q_   = ws + 9437184;           // 98,304
  float* ctx_ = ws + 9535488;           // 393,216
  float* ent_ = ws + 9928704;           // 393,216
  float* ctxv = ws + 10321920;          // 3,072
  float* C1   = ws + 10324992;          // 3,072
  float* invs = ws + 10328064;          // 6,144

  float* out_ent   = (float*)d_out;           // 393,216
  float* out_graph = out_ent + 393216;        // 65,536
  float* out_mask  = out_ent + 458752;        // 512

  // 0. Wk/Wv -> transposed bf16
  wconv_kernel<<<dim3(12, 12, 2), 256, 0, stream>>>(Wk, Wv, WtK, WtV);
  // 1. x = emb + pos (bf16)
  posadd_bf16_kernel<<<1536, 256, 0, stream>>>(emb, pos, xb);
  // 2. context = mean_s (emb+pos)
  ctxmean_kernel<<<48, 256, 0, stream>>>(emb, pos, ctxv);
  // 3. q = lib @ Wq + bq
  gemm768_kernel<<<dim3(2, 12), 256, 0, stream>>>(lib, Wq, bq, q_, 128);
  // 4. k2/v2 = x @ Wk/Wv + b via bf16 MFMA, transposed to (B,H,S,64)
  kv_mfma_kernel<<<dim3(64, 12), 256, 0, stream>>>(xb, WtK, WtV, bk, bv, k2, v2);
  // 5. attention -> ctx (B,N,H*K), invsum (B,H,N)
  attn2_kernel<<<384, 256, 0, stream>>>(q_, k2, v2, ctx_, invs);
  // 6. entity mask
  mask_kernel<<<1, 512, 0, stream>>>(invs, out_mask);
  // 7. entities = ctx @ Wo + bo
  gemm768_kernel<<<dim3(8, 12), 256, 0, stream>>>(ctx_, Wo, bo, ent_, 512);
  // 8. masked entities out
  entmask_kernel<<<512, 256, 0, stream>>>(ent_, out_mask, out_ent);
  // 9. fused per-entity projections for edge MLPs (A1,B1,Ag,Bg)
  ProjParams pp;
  pp.W[0] = W1;              pp.bias[0] = nullptr; pp.C[0] = A1;
  pp.W[1] = W1 + 589824;     pp.bias[1] = nullptr; pp.C[1] = B1;
  pp.W[2] = Wg1;             pp.bias[2] = bg1;     pp.C[2] = Ag;
  pp.W[3] = Wg1 + 589824;    pp.bias[3] = nullptr; pp.C[3] = Bg;
  gemm768x4_kernel<<<dim3(8, 48), 256, 0, stream>>>(ent_, pp);
  // 10. C1 = context @ W1d + b1
  gemm768_kernel<<<dim3(1, 12), 256, 0, stream>>>(ctxv, W1 + 1537 * 768, b1, C1, 4);
  // 11. fused edge refinement (3 steps) + gate + entity masking
  refine_kernel<<<2048, 256, 0, stream>>>(A1, B1, C1, W1 + 1536 * 768, W2, b2,
                                          Ag, Bg, Wg2, bg2, ginit, out_mask,
                                          out_graph);
}

// Round 9
// 547.767 us; speedup vs baseline: 1.7936x; 1.1234x over previous
//
#include <hip/hip_runtime.h>
#include <hip/hip_bf16.h>
#include <math.h>

namespace {
constexpr int SEQ  = 1024;
constexpr int NE   = 128;

typedef float f32x4  __attribute__((ext_vector_type(4)));
typedef short bf16x8 __attribute__((ext_vector_type(8)));

__device__ __forceinline__ float rcp_fast(float x) {
  return __builtin_amdgcn_rcpf(x);
}

__device__ __forceinline__ float gelu_fast(float x) {
  float x2 = x * x;
  float t = fmaf(x2, -0.1029443f, -2.3022093f);
  return x * rcp_fast(1.0f + exp2f(x * t));
}

__device__ __forceinline__ float tanh_fast(float x) {
  return 1.0f - 2.0f * rcp_fast(1.0f + exp2f(x * 2.8853901f));
}

__device__ __forceinline__ float sigmoid_fast(float x) {
  return rcp_fast(1.0f + exp2f(x * -1.4426950f));
}

__device__ __forceinline__ ushort f2bf(float f) {
  union { float f; unsigned u; } c; c.f = f;
  unsigned u = c.u;
  u += 0x7FFF + ((u >> 16) & 1);            // RNE
  return (ushort)(u >> 16);
}

// ---------------------------------------------------------------- pos add -> bf16 x
__global__ __launch_bounds__(256) void posadd_bf16_kernel(
    const float* __restrict__ emb, const float* __restrict__ pos,
    ushort* __restrict__ xb) {
  int i = blockIdx.x * 256 + threadIdx.x;      // 8-float chunk; total 393216
  const int perB = SEQ * 768 / 8;              // 98304
  int pi = i - (i / perB) * perB;
  float4 e0 = ((const float4*)emb)[i * 2];
  float4 e1 = ((const float4*)emb)[i * 2 + 1];
  float4 p0 = ((const float4*)pos)[pi * 2];
  float4 p1 = ((const float4*)pos)[pi * 2 + 1];
  ushort o[8];
  o[0] = f2bf(e0.x + p0.x); o[1] = f2bf(e0.y + p0.y);
  o[2] = f2bf(e0.z + p0.z); o[3] = f2bf(e0.w + p0.w);
  o[4] = f2bf(e1.x + p1.x); o[5] = f2bf(e1.y + p1.y);
  o[6] = f2bf(e1.z + p1.z); o[7] = f2bf(e1.w + p1.w);
  *(uint4*)&xb[(size_t)i * 8] = *(uint4*)o;
}

// ---------------------------------------------------------------- weight transpose-convert: W[k][n] f32 -> Wt[n][k] bf16
__global__ __launch_bounds__(256) void wconv_kernel(
    const float* __restrict__ Wk, const float* __restrict__ Wv,
    ushort* __restrict__ WtK, ushort* __restrict__ WtV) {
  const float* __restrict__ W  = blockIdx.z ? Wv : Wk;
  ushort* __restrict__ Wt = blockIdx.z ? WtV : WtK;
  const int k0 = blockIdx.x * 64, n0 = blockIdx.y * 64;
  __shared__ ushort sT[64][72];               // [n][k], padded
  const int t = threadIdx.x;
  const int rr = t >> 4, c4 = (t & 15) * 4;
#pragma unroll
  for (int i = 0; i < 4; ++i) {
    int r = rr + 16 * i;
    float4 v = *(const float4*)&W[(size_t)(k0 + r) * 768 + n0 + c4];
    sT[c4 + 0][r] = f2bf(v.x);
    sT[c4 + 1][r] = f2bf(v.y);
    sT[c4 + 2][r] = f2bf(v.z);
    sT[c4 + 3][r] = f2bf(v.w);
  }
  __syncthreads();
#pragma unroll
  for (int j = 0; j < 2; ++j) {
    int cid = t + 256 * j;
    int nr = cid >> 3, kc8 = (cid & 7) * 8;
    *(uint4*)&Wt[(size_t)(n0 + nr) * 768 + k0 + kc8] = *(uint4*)&sT[nr][kc8];
  }
}

// ---------------------------------------------------------------- context mean (from emb+pos directly)
__global__ __launch_bounds__(256) void ctxmean_kernel(
    const float* __restrict__ emb, const float* __restrict__ pos,
    float* __restrict__ ctxv) {
  int b = blockIdx.x / 12, chunk = blockIdx.x % 12;
  int lane = threadIdx.x & 63, sg = threadIdx.x >> 6;
  int d = chunk * 64 + lane;
  float acc = 0.f;
  const float* eb = emb + ((size_t)b * SEQ + sg) * 768 + d;
  const float* pp = pos + (size_t)sg * 768 + d;
  for (int s = sg; s < SEQ; s += 4) {
    acc += *eb + *pp;
    eb += 4 * 768; pp += 4 * 768;
  }
  __shared__ float red[4][64];
  red[sg][lane] = acc;
  __syncthreads();
  if (threadIdx.x < 64) {
    float t = red[0][threadIdx.x] + red[1][threadIdx.x] +
              red[2][threadIdx.x] + red[3][threadIdx.x];
    ctxv[b * 768 + chunk * 64 + threadIdx.x] = t * (1.0f / 1024.0f);
  }
}

// ---------------------------------------------------------------- small GEMM  C[Mx768] = A[Mx768] @ W[768x768] (+bias)
__global__ __launch_bounds__(256) void gemm768_kernel(
    const float* __restrict__ A, const float* __restrict__ W,
    const float* __restrict__ bias, float* __restrict__ C, int M) {
  __shared__ __align__(16) float sA[16][68];
  __shared__ __align__(16) float sB[16][68];
  const int bm = blockIdx.x * 64;
  const int bn = blockIdx.y * 64;
  const int tid = threadIdx.x;
  const int tm = (tid >> 4) * 4;
  const int tn = (tid & 15) * 4;
  const int lm = tid >> 2, lkq = (tid & 3) * 4;
  const int lkk = tid >> 4, lnq = (tid & 15) * 4;
  float acc[4][4] = {};
  for (int k0 = 0; k0 < 768; k0 += 16) {
    float4 av = make_float4(0.f, 0.f, 0.f, 0.f);
    if (bm + lm < M) av = *(const float4*)&A[(size_t)(bm + lm) * 768 + k0 + lkq];
    float4 wv = *(const float4*)&W[(size_t)(k0 + lkk) * 768 + bn + lnq];
    __syncthreads();
    sA[lkq + 0][lm] = av.x; sA[lkq + 1][lm] = av.y;
    sA[lkq + 2][lm] = av.z; sA[lkq + 3][lm] = av.w;
    *(float4*)&sB[lkk][lnq] = wv;
    __syncthreads();
#pragma unroll
    for (int kk = 0; kk < 16; ++kk) {
      float4 a = *(const float4*)&sA[kk][tm];
      float4 w = *(const float4*)&sB[kk][tn];
      acc[0][0] += a.x * w.x; acc[0][1] += a.x * w.y; acc[0][2] += a.x * w.z; acc[0][3] += a.x * w.w;
      acc[1][0] += a.y * w.x; acc[1][1] += a.y * w.y; acc[1][2] += a.y * w.z; acc[1][3] += a.y * w.w;
      acc[2][0] += a.z * w.x; acc[2][1] += a.z * w.y; acc[2][2] += a.z * w.z; acc[2][3] += a.z * w.w;
      acc[3][0] += a.w * w.x; acc[3][1] += a.w * w.y; acc[3][2] += a.w * w.z; acc[3][3] += a.w * w.w;
    }
  }
#pragma unroll
  for (int i = 0; i < 4; ++i) {
    int row = bm + tm + i;
    if (row < M) {
#pragma unroll
      for (int j = 0; j < 4; ++j) {
        float o = acc[i][j];
        if (bias) o += bias[bn + tn + j];
        C[(size_t)row * 768 + bn + tn + j] = o;
      }
    }
  }
}

// ---------------------------------------------------------------- 4-way fused projection GEMM (shared A, M=512)
struct ProjParams {
  const float* W[4];
  const float* bias[4];
  float* C[4];
};

__global__ __launch_bounds__(256) void gemm768x4_kernel(
    const float* __restrict__ A, ProjParams pp) {
  __shared__ __align__(16) float sA[16][68];
  __shared__ __align__(16) float sB[16][68];
  const int sel = blockIdx.y / 12;
  const float* W = pp.W[sel];
  const float* bias = pp.bias[sel];
  float* C = pp.C[sel];
  const int bm = blockIdx.x * 64;
  const int bn = (blockIdx.y % 12) * 64;
  const int tid = threadIdx.x;
  const int tm = (tid >> 4) * 4;
  const int tn = (tid & 15) * 4;
  const int lm = tid >> 2, lkq = (tid & 3) * 4;
  const int lkk = tid >> 4, lnq = (tid & 15) * 4;
  float acc[4][4] = {};
  for (int k0 = 0; k0 < 768; k0 += 16) {
    float4 av = *(const float4*)&A[(size_t)(bm + lm) * 768 + k0 + lkq];
    float4 wv = *(const float4*)&W[(size_t)(k0 + lkk) * 768 + bn + lnq];
    __syncthreads();
    sA[lkq + 0][lm] = av.x; sA[lkq + 1][lm] = av.y;
    sA[lkq + 2][lm] = av.z; sA[lkq + 3][lm] = av.w;
    *(float4*)&sB[lkk][lnq] = wv;
    __syncthreads();
#pragma unroll
    for (int kk = 0; kk < 16; ++kk) {
      float4 a = *(const float4*)&sA[kk][tm];
      float4 w = *(const float4*)&sB[kk][tn];
      acc[0][0] += a.x * w.x; acc[0][1] += a.x * w.y; acc[0][2] += a.x * w.z; acc[0][3] += a.x * w.w;
      acc[1][0] += a.y * w.x; acc[1][1] += a.y * w.y; acc[1][2] += a.y * w.z; acc[1][3] += a.y * w.w;
      acc[2][0] += a.z * w.x; acc[2][1] += a.z * w.y; acc[2][2] += a.z * w.z; acc[2][3] += a.z * w.w;
      acc[3][0] += a.w * w.x; acc[3][1] += a.w * w.y; acc[3][2] += a.w * w.z; acc[3][3] += a.w * w.w;
    }
  }
#pragma unroll
  for (int i = 0; i < 4; ++i) {
    int row = bm + tm + i;
#pragma unroll
    for (int j = 0; j < 4; ++j) {
      float o = acc[i][j];
      if (bias) o += bias[bn + tn + j];
      C[(size_t)row * 768 + bn + tn + j] = o;
    }
  }
}

// ---------------------------------------------------------------- fused K+V GEMM via bf16 MFMA
__global__ __launch_bounds__(256) void kv_mfma_kernel(
    const ushort* __restrict__ xb,       // (4096,768) bf16
    const ushort* __restrict__ WtK,      // (768 n, 768 k) bf16
    const ushort* __restrict__ WtV,
    const float* __restrict__ bk, const float* __restrict__ bv,
    float* __restrict__ k2, float* __restrict__ v2) {
  __shared__ ushort sA[64][40];          // [m][k] bf16, pad 40
  __shared__ ushort sBt[128][40];        // [n][k] bf16
  const int bm = blockIdx.x * 64;
  const bool isV = blockIdx.y >= 6;
  const int bn = (blockIdx.y % 6) * 128;
  const ushort* __restrict__ Wt = isV ? WtV : WtK;
  const float* __restrict__ bias = isV ? bv : bk;
  float* __restrict__ out = isV ? v2 : k2;
  const int t = threadIdx.x;
  const int ar = t >> 2, ac8 = (t & 3) * 8;
  const int wr = t >> 2, wc8 = (t & 3) * 8;

  const ushort* __restrict__ Axp = xb + (size_t)(bm + ar) * 768 + ac8;
  const ushort* __restrict__ Wp0 = Wt + (size_t)(bn + wr) * 768 + wc8;
  const ushort* __restrict__ Wp1 = Wt + (size_t)(bn + wr + 64) * 768 + wc8;

  uint4 ra  = *(const uint4*)(Axp);
  uint4 rw0 = *(const uint4*)(Wp0);
  uint4 rw1 = *(const uint4*)(Wp1);

  const int lane = t & 63;
  const int w = t >> 6;
  const int lrow = lane & 15;
  const int lk8 = (lane >> 4) * 8;

  f32x4 acc[8] = {};
  for (int k0 = 0; k0 < 768; k0 += 32) {
    __syncthreads();
    *(uint4*)&sA[ar][ac8] = ra;
    *(uint4*)&sBt[wr][wc8] = rw0;
    *(uint4*)&sBt[wr + 64][wc8] = rw1;
    __syncthreads();
    if (k0 + 32 < 768) {
      ra  = *(const uint4*)(Axp + k0 + 32);
      rw0 = *(const uint4*)(Wp0 + k0 + 32);
      rw1 = *(const uint4*)(Wp1 + k0 + 32);
    }
    bf16x8 a = *(const bf16x8*)&sA[w * 16 + lrow][lk8];
#pragma unroll
    for (int nf = 0; nf < 8; ++nf) {
      bf16x8 b = *(const bf16x8*)&sBt[nf * 16 + lrow][lk8];
      acc[nf] = __builtin_amdgcn_mfma_f32_16x16x32_bf16(a, b, acc[nf], 0, 0, 0);
    }
  }

  const int bidx = bm >> 10;
  const int s_base = bm & 1023;
  const int h0 = bn >> 6;
  const int rg = (lane >> 4) * 4;
#pragma unroll
  for (int nf = 0; nf < 8; ++nf) {
    int nl = nf * 16 + lrow;
    int h = h0 + (nl >> 6);
    int c = nl & 63;
    float bsv = bias[bn + nl];
    float* op = out + (((size_t)(bidx * 12 + h)) * 1024 + s_base + w * 16 + rg) * 64 + c;
#pragma unroll
    for (int r = 0; r < 4; ++r)
      op[(size_t)r * 64] = acc[nf][r] + bsv;
  }
}

// ---------------------------------------------------------------- flash attention (online softmax), 16 queries/block
// LDS ~45KB -> 3 blocks/CU; direct global->LDS staging (no cross-barrier reg arrays)
__global__ __launch_bounds__(256) void attn2_kernel(
    const float* __restrict__ q, const float* __restrict__ k2,
    const float* __restrict__ v2, float* __restrict__ ctx,
    float* __restrict__ invsum) {
  __shared__ float4 sK[2048];             // 32KB; aliased as part[] at end
  __shared__ float p[16][144];            // chunk scores, stride 144
  __shared__ float4 sQ[16][16];
  __shared__ float frow[16];
  __shared__ float linv[16];

  // XCD-aware remap: one (b,h)'s 8 q-group blocks land on one XCD
  const int xcd = blockIdx.x & 7;
  const int slot = blockIdx.x >> 3;       // 0..47
  const int bh = xcd * 6 + (slot >> 3);   // 0..47
  const int ng = slot & 7;
  const int b = bh / 12, h = bh % 12;
  const int t = threadIdx.x;

  {  // stage Q, fold 1/sqrt(64)
    int nn = t >> 4, dq = t & 15;
    float4 qv = *(const float4*)&q[(size_t)(ng * 16 + nn) * 768 + h * 64 + dq * 4];
    qv.x *= 0.125f; qv.y *= 0.125f; qv.z *= 0.125f; qv.w *= 0.125f;
    sQ[nn][dq] = qv;
  }
  const float4* kbh = (const float4*)(k2 + ((size_t)(b * 12 + h)) * 1024 * 64);
  const float4* vbh = (const float4*)(v2 + ((size_t)(b * 12 + h)) * 1024 * 64);

  // role indices
  const int g = t & 31, npair = t >> 5;           // QK: rows n0,n1; 4 s each
  const int n0 = npair * 2, n1 = n0 + 1;
  const int rn = t >> 4, sub = t & 15;            // softmax rows
  const int dq = t & 15, nq = (t >> 4) & 3, sq = t >> 6;  // PV

  float m_run = -1e30f, sum_run = 0.f;
  float4 acc[4] = {};

  for (int c = 0; c < 8; ++c) {
    __syncthreads();                       // sK free (prev PV done)
#pragma unroll
    for (int w = 0; w < 8; ++w) {          // K chunk -> LDS (swizzled), short-lived temps
      int fi = w * 256 + t;
      int sl = fi >> 4, dd = fi & 15;
      float4 tmp = kbh[c * 2048 + fi];
      sK[sl * 16 + (dd ^ (sl & 15))] = tmp;
    }
    __syncthreads();

    // ---- scores for this chunk ----
    float4 a0[4] = {}, a1[4] = {};
#pragma unroll
    for (int d0 = 0; d0 < 16; ++d0) {
      float4 q0 = sQ[n0][d0];
      float4 q1 = sQ[n1][d0];
      int slot2 = d0 ^ (g & 15);
#pragma unroll
      for (int u = 0; u < 4; ++u) {
        float4 kv = sK[(g + 32 * u) * 16 + slot2];
        a0[u].x += q0.x * kv.x; a0[u].y += q0.y * kv.y;
        a0[u].z += q0.z * kv.z; a0[u].w += q0.w * kv.w;
        a1[u].x += q1.x * kv.x; a1[u].y += q1.y * kv.y;
        a1[u].z += q1.z * kv.z; a1[u].w += q1.w * kv.w;
      }
    }
#pragma unroll
    for (int u = 0; u < 4; ++u) {
      int s = g + 32 * u;
      p[n0][s] = a0[u].x + a0[u].y + a0[u].z + a0[u].w;
      p[n1][s] = a1[u].x + a1[u].y + a1[u].z + a1[u].w;
    }
    __syncthreads();                       // p done; score reads of sK done

    // ---- online softmax update ----
    float cm = -1e30f;
#pragma unroll
    for (int u = 0; u < 8; ++u) cm = fmaxf(cm, p[rn][sub + 16 * u]);
    cm = fmaxf(cm, __shfl_xor(cm, 1)); cm = fmaxf(cm, __shfl_xor(cm, 2));
    cm = fmaxf(cm, __shfl_xor(cm, 4)); cm = fmaxf(cm, __shfl_xor(cm, 8));
    float mn = fmaxf(m_run, cm);
    float f = __expf(m_run - mn);
    float csum = 0.f;
#pragma unroll
    for (int u = 0; u < 8; ++u) {
      float e = __expf(p[rn][sub + 16 * u] - mn);
      p[rn][sub + 16 * u] = e;
      csum += e;
    }
    csum += __shfl_xor(csum, 1); csum += __shfl_xor(csum, 2);
    csum += __shfl_xor(csum, 4); csum += __shfl_xor(csum, 8);
    sum_run = sum_run * f + csum;
    m_run = mn;
    if (sub == 0) frow[rn] = f;

#pragma unroll
    for (int w = 0; w < 8; ++w) {          // V chunk -> LDS (same buffer); loads hoist above softmax
      int fi = w * 256 + t;
      int sl = fi >> 4, dd = fi & 15;
      float4 tmp = vbh[c * 2048 + fi];
      sK[sl * 16 + (dd ^ (sl & 15))] = tmp;
    }
    __syncthreads();                       // V + frow + exp(p) ready

    // ---- PV accumulate with rescale ----
#pragma unroll
    for (int i = 0; i < 4; ++i) {
      float fr = frow[nq * 4 + i];
      acc[i].x *= fr; acc[i].y *= fr; acc[i].z *= fr; acc[i].w *= fr;
    }
#pragma unroll 2
    for (int v4 = 0; v4 < 32; v4 += 4) {
      int sl0 = sq * 32 + v4;
      float pr[4][4];
#pragma unroll
      for (int i = 0; i < 4; ++i)
        *(float4*)&pr[i][0] = *(const float4*)&p[nq * 4 + i][sl0];
#pragma unroll
      for (int u = 0; u < 4; ++u) {
        int sl = sl0 + u;
        float4 vv = sK[sl * 16 + (dq ^ (sl & 15))];
#pragma unroll
        for (int i = 0; i < 4; ++i) {
          float pw = pr[i][u];
          acc[i].x += pw * vv.x; acc[i].y += pw * vv.y;
          acc[i].z += pw * vv.z; acc[i].w += pw * vv.w;
        }
      }
    }
  }

  // activity = 1/sum
  if (sub == 0) {
    float inv = 1.0f / sum_run;
    linv[rn] = inv;
    invsum[(b * 12 + h) * 128 + ng * 16 + rn] = inv;
  }
  __syncthreads();                         // last PV reads of sK done
  // partial-sum reduction, part[] aliased into sK
#pragma unroll
  for (int i = 0; i < 4; ++i)
    sK[((sq * 4 + nq) * 4 + i) * 16 + dq] = acc[i];
  __syncthreads();
  {
    int n = t >> 4, dqq = t & 15;
    float4 r0 = sK[((0 * 4 + (n >> 2)) * 4 + (n & 3)) * 16 + dqq];
    float4 r1 = sK[((1 * 4 + (n >> 2)) * 4 + (n & 3)) * 16 + dqq];
    float4 r2 = sK[((2 * 4 + (n >> 2)) * 4 + (n & 3)) * 16 + dqq];
    float4 r3 = sK[((3 * 4 + (n >> 2)) * 4 + (n & 3)) * 16 + dqq];
    float inv = linv[n];
    float4 o;
    o.x = (r0.x + r1.x + r2.x + r3.x) * inv;
    o.y = (r0.y + r1.y + r2.y + r3.y) * inv;
    o.z = (r0.z + r1.z + r2.z + r3.z) * inv;
    o.w = (r0.w + r1.w + r2.w + r3.w) * inv;
    *(float4*)&ctx[(size_t)(b * 128 + ng * 16 + n) * 768 + h * 64 + dqq * 4] = o;
  }
}

// ---------------------------------------------------------------- entity mask
__global__ void mask_kernel(const float* __restrict__ invsum,
                            float* __restrict__ mask_out) {
  int t = threadIdx.x;                   // 512 = B*N
  int b = t >> 7, n = t & 127;
  float a = 0.f;
  for (int h = 0; h < 12; ++h) a = fmaxf(a, invsum[(b * 12 + h) * 128 + n]);
  mask_out[t] = (a > 0.001f) ? 1.0f : 0.0f;
}

// ---------------------------------------------------------------- masked entities out
__global__ __launch_bounds__(256) void entmask_kernel(
    const float* __restrict__ ent, const float* __restrict__ mask,
    float* __restrict__ out) {
  int bi = blockIdx.x;                   // b*128+i
  float m = mask[bi];
  for (int e = threadIdx.x; e < 768; e += 256)
    out[(size_t)bi * 768 + e] = ent[(size_t)bi * 768 + e] * m;
}

// ---------------------------------------------------------------- fused edge refinement + gate + mask
__global__ __launch_bounds__(256) void refine_kernel(
    const float* __restrict__ A1, const float* __restrict__ B1,
    const float* __restrict__ C1, const float* __restrict__ w1g,
    const float* __restrict__ W2, const float* __restrict__ b2,
    const float* __restrict__ Ag, const float* __restrict__ Bg,
    const float* __restrict__ Wg2, const float* __restrict__ bg2,
    const float* __restrict__ graph_init, const float* __restrict__ mask,
    float* __restrict__ graph_out) {
  const int bi = blockIdx.x >> 2;        // b*128 + i
  const int jq = blockIdx.x & 3;         // j-quarter
  const int b = bi >> 7;
  const int lane = threadIdx.x & 63, wv = threadIdx.x >> 6;

  float base[12], w1gr[12], w2r[12], agr[12], wg2r[12];
#pragma unroll
  for (int r = 0; r < 12; ++r) {
    int e = r * 64 + lane;
    base[r] = A1[(size_t)bi * 768 + e] + C1[b * 768 + e];
    w1gr[r] = w1g[e];
    w2r[r]  = W2[e];
    agr[r]  = Ag[(size_t)bi * 768 + e];
    wg2r[r] = Wg2[e];
  }
  const float b2s = b2[0], bg2s = bg2[0];
  const float mi = mask[bi];

  const int jend = jq * 32 + 32;
  for (int j = jq * 32 + wv; j < jend; j += 4) {
    float g = graph_init[(size_t)bi * 128 + j] * 1.6f - 0.8f;
    const float* B1j = &B1[((size_t)(b * NE + j)) * 768 + lane];
    const float* Bgj = &Bg[((size_t)(b * NE + j)) * 768 + lane];
    float pre[12], gpre[12];
#pragma unroll
    for (int r = 0; r < 12; ++r) {
      pre[r]  = base[r] + B1j[r * 64];
      gpre[r] = agr[r] + Bgj[r * 64];
    }
#pragma unroll
    for (int st = 0; st < 3; ++st) {
      float acc = 0.f;
#pragma unroll
      for (int r = 0; r < 12; ++r) {
        float hx = pre[r] + g * w1gr[r];
        acc += gelu_fast(hx) * w2r[r];
      }
      acc += __shfl_xor(acc, 1);  acc += __shfl_xor(acc, 2);
      acc += __shfl_xor(acc, 4);  acc += __shfl_xor(acc, 8);
      acc += __shfl_xor(acc, 16); acc += __shfl_xor(acc, 32);
      g += tanh_fast(acc + b2s);
    }
    float gacc = 0.f;
#pragma unroll
    for (int r = 0; r < 12; ++r) gacc += gelu_fast(gpre[r]) * wg2r[r];
    gacc += __shfl_xor(gacc, 1);  gacc += __shfl_xor(gacc, 2);
    gacc += __shfl_xor(gacc, 4);  gacc += __shfl_xor(gacc, 8);
    gacc += __shfl_xor(gacc, 16); gacc += __shfl_xor(gacc, 32);
    float gate = sigmoid_fast(gacc + bg2s);
    if (lane == 0)
      graph_out[(size_t)bi * 128 + j] = g * gate * mi * mask[b * NE + j];
  }
}

}  // namespace

extern "C" void kernel_launch(void* const* d_in, const int* in_sizes, int n_in,
                              void* d_out, int out_size, void* d_ws, size_t ws_size,
                              hipStream_t stream) {
  const float* emb  = (const float*)d_in[0];
  const float* ginit= (const float*)d_in[1];
  const float* lib  = (const float*)d_in[2];
  const float* pos  = (const float*)d_in[3];
  const float* Wq   = (const float*)d_in[4];
  const float* bq   = (const float*)d_in[5];
  const float* Wk   = (const float*)d_in[6];
  const float* bk   = (const float*)d_in[7];
  const float* Wv   = (const float*)d_in[8];
  const float* bv   = (const float*)d_in[9];
  const float* Wo   = (const float*)d_in[10];
  const float* bo   = (const float*)d_in[11];
  const float* W1   = (const float*)d_in[12];
  const float* b1   = (const float*)d_in[13];
  const float* W2   = (const float*)d_in[14];
  const float* b2   = (const float*)d_in[15];
  const float* Wg1  = (const float*)d_in[16];
  const float* bg1  = (const float*)d_in[17];
  const float* Wg2  = (const float*)d_in[18];
  const float* bg2  = (const float*)d_in[19];

  float* ws = (float*)d_ws;
  float* k2   = ws + 0;                 // (B,H,S,64)  3,145,728
  float* v2   = ws + 3145728;           // (B,H,S,64)  3,145,728
  ushort* xb  = (ushort*)(ws + 6291456);     // bf16 x; dead after kv_mfma
  float* A1   = ws + 6291456;           // reuse after kv
  float* B1   = ws + 6684672;
  float* Ag   = ws + 7077888;
  float* Bg   = ws + 7471104;           // ends 7864320
  ushort* WtK = (ushort*)(ws + 7864320);
  ushort* WtV = WtK + 589824;
  float* q_   = ws + 9437184;           // 98,304
  float* ctx_ = ws + 9535488;           // 393,216
  float* ent_ = ws + 9928704;           // 393,216
  float* ctxv = ws + 10321920;          // 3,072
  float* C1   = ws + 10324992;          // 3,072
  float* invs = ws + 10328064;          // 6,144

  float* out_ent   = (float*)d_out;           // 393,216
  float* out_graph = out_ent + 393216;        // 65,536
  float* out_mask  = out_ent + 458752;        // 512

  // 0. Wk/Wv -> transposed bf16
  wconv_kernel<<<dim3(12, 12, 2), 256, 0, stream>>>(Wk, Wv, WtK, WtV);
  // 1. x = emb + pos (bf16)
  posadd_bf16_kernel<<<1536, 256, 0, stream>>>(emb, pos, xb);
  // 2. context = mean_s (emb+pos)
  ctxmean_kernel<<<48, 256, 0, stream>>>(emb, pos, ctxv);
  // 3. q = lib @ Wq + bq
  gemm768_kernel<<<dim3(2, 12), 256, 0, stream>>>(lib, Wq, bq, q_, 128);
  // 4. k2/v2 = x @ Wk/Wv + b via bf16 MFMA, transposed to (B,H,S,64)
  kv_mfma_kernel<<<dim3(64, 12), 256, 0, stream>>>(xb, WtK, WtV, bk, bv, k2, v2);
  // 5. attention -> ctx (B,N,H*K), invsum (B,H,N)
  attn2_kernel<<<384, 256, 0, stream>>>(q_, k2, v2, ctx_, invs);
  // 6. entity mask
  mask_kernel<<<1, 512, 0, stream>>>(invs, out_mask);
  // 7. entities = ctx @ Wo + bo
  gemm768_kernel<<<dim3(8, 12), 256, 0, stream>>>(ctx_, Wo, bo, ent_, 512);
  // 8. masked entities out
  entmask_kernel<<<512, 256, 0, stream>>>(ent_, out_mask, out_ent);
  // 9. fused per-entity projections for edge MLPs (A1,B1,Ag,Bg)
  ProjParams pp;
  pp.W[0] = W1;              pp.bias[0] = nullptr; pp.C[0] = A1;
  pp.W[1] = W1 + 589824;     pp.bias[1] = nullptr; pp.C[1] = B1;
  pp.W[2] = Wg1;             pp.bias[2] = bg1;     pp.C[2] = Ag;
  pp.W[3] = Wg1 + 589824;    pp.bias[3] = nullptr; pp.C[3] = Bg;
  gemm768x4_kernel<<<dim3(8, 48), 256, 0, stream>>>(ent_, pp);
  // 10. C1 = context @ W1d + b1
  gemm768_kernel<<<dim3(1, 12), 256, 0, stream>>>(ctxv, W1 + 1537 * 768, b1, C1, 4);
  // 11. fused edge refinement (3 steps) + gate + entity masking
  refine_kernel<<<2048, 256, 0, stream>>>(A1, B1, C1, W1 + 1536 * 768, W2, b2,
                                          Ag, Bg, Wg2, bg2, ginit, out_mask,
                                          out_graph);
}